// Round 9
// baseline (346.454 us; speedup 1.0000x reference)
//
#include <hip/hip_runtime.h>
#include <math.h>

#define VOCAB 32000
#define EMBED 512
#define HID   1024
#define BATCH 64
#define SEQ   512

// d_out layout (floats): pred[64*32000]=0 .. 2048000 ; h1 @2048000 ; c1 @2113536 ; attn @2179072
#define OUT_H1   2048000
#define OUT_C1   2113536
#define OUT_ATTN 2179072

typedef __bf16 bf16x8 __attribute__((ext_vector_type(8)));
typedef float  f32x4  __attribute__((ext_vector_type(4)));

__device__ __forceinline__ unsigned short f2bf(float f) {
  unsigned int u = __builtin_bit_cast(unsigned int, f);
  u += 0x7fffu + ((u >> 16) & 1u);   // round-to-nearest-even
  return (unsigned short)(u >> 16);
}
__device__ __forceinline__ float bf2f(unsigned int u) {
  return __builtin_bit_cast(float, u << 16);
}

// fast tanh: (e^{2x}-1)/(e^{2x}+1) via hw exp2; clamp avoids inf/inf
__device__ __forceinline__ float fast_tanh(float x) {
  float cx = fminf(fmaxf(x, -15.f), 15.f);
  float t = __builtin_amdgcn_exp2f(cx * 2.8853900817779268f);  // e^{2x}
  return (t - 1.f) / (t + 1.f);
}

// async 16B/lane global->LDS; lds ptr must be wave-uniform (HW: base + lane*16)
__device__ __forceinline__ void gload16(const unsigned short* g, unsigned short* l) {
  __builtin_amdgcn_global_load_lds(
      (const __attribute__((address_space(1))) void*)g,
      (__attribute__((address_space(3))) void*)l, 16, 0, 0);
}

// 16 f32 -> 16 bf16 (RNE bit-trick), 32B to LDS
__device__ __forceinline__ void stage16(const float* __restrict__ src, unsigned short* dst) {
  float4 f0 = *(const float4*)(src + 0);
  float4 f1 = *(const float4*)(src + 4);
  float4 f2 = *(const float4*)(src + 8);
  float4 f3 = *(const float4*)(src + 12);
  union { unsigned short us[16]; uint4 u4[2]; } p;
  p.us[0]=f2bf(f0.x);  p.us[1]=f2bf(f0.y);  p.us[2]=f2bf(f0.z);  p.us[3]=f2bf(f0.w);
  p.us[4]=f2bf(f1.x);  p.us[5]=f2bf(f1.y);  p.us[6]=f2bf(f1.z);  p.us[7]=f2bf(f1.w);
  p.us[8]=f2bf(f2.x);  p.us[9]=f2bf(f2.y);  p.us[10]=f2bf(f2.z); p.us[11]=f2bf(f2.w);
  p.us[12]=f2bf(f3.x); p.us[13]=f2bf(f3.y); p.us[14]=f2bf(f3.z); p.us[15]=f2bf(f3.w);
  *(uint4*)(dst + 0) = p.u4[0];
  *(uint4*)(dst + 8) = p.u4[1];
}

// ==== prep: fuses {enc->bf16, W2->bf16, zero scores+ctx, dh=h0@W1^T} ====
__global__ void prep_kernel(const float* __restrict__ enc, unsigned short* __restrict__ encb,
                            const float* __restrict__ W2, unsigned short* __restrict__ W2b,
                            float* __restrict__ zr,
                            const float* __restrict__ h0, const float* __restrict__ W1,
                            float* __restrict__ dh) {
  __shared__ float hs[HID];
  int bid = blockIdx.x, t = threadIdx.x;
  if (bid < 2048) {                       // enc: 4,194,304 groups of 8, grid-stride
    int i = bid * 256 + t;
    for (; i < BATCH * SEQ * HID / 8; i += 2048 * 256) {
      const float* s = enc + (size_t)i * 8;
      float4 f0 = *(const float4*)s;
      float4 f1 = *(const float4*)(s + 4);
      union { unsigned short us[8]; uint4 u; } p;
      p.us[0]=f2bf(f0.x); p.us[1]=f2bf(f0.y); p.us[2]=f2bf(f0.z); p.us[3]=f2bf(f0.w);
      p.us[4]=f2bf(f1.x); p.us[5]=f2bf(f1.y); p.us[6]=f2bf(f1.z); p.us[7]=f2bf(f1.w);
      *(uint4*)(encb + (size_t)i * 8) = p.u;
    }
  } else if (bid < 2560) {                // W2: 131,072 groups of 8, exact
    int i = (bid - 2048) * 256 + t;
    const float* s = W2 + (size_t)i * 8;
    float4 f0 = *(const float4*)s;
    float4 f1 = *(const float4*)(s + 4);
    union { unsigned short us[8]; uint4 u; } p;
    p.us[0]=f2bf(f0.x); p.us[1]=f2bf(f0.y); p.us[2]=f2bf(f0.z); p.us[3]=f2bf(f0.w);
    p.us[4]=f2bf(f1.x); p.us[5]=f2bf(f1.y); p.us[6]=f2bf(f1.z); p.us[7]=f2bf(f1.w);
    *(uint4*)(W2b + (size_t)i * 8) = p.u;
  } else if (bid < 2656) {                // zero scores+ctx: 98304 floats
    int i = (bid - 2560) * 256 + t;
    *(float4*)(zr + (size_t)i * 4) = (float4){0.f, 0.f, 0.f, 0.f};
  } else {                                // dh: 256 blocks (64 b x 4 k-blocks)
    int bb = bid - 2656;
    int b = bb >> 2, kblk = bb & 3;
    for (int i = t; i < HID; i += 256) hs[i] = h0[b * HID + i];
    __syncthreads();
    int k = kblk * 256 + t;
    const float* w = W1 + (size_t)k * HID;
    float acc = 0.f;
    for (int hh = 0; hh < HID; hh += 4) {
      float4 wv = *(const float4*)(w + hh);
      float4 hv = *(const float4*)(hs + hh);
      acc += wv.x * hv.x + wv.y * hv.y + wv.z * hv.z + wv.w * hv.w;
    }
    dh[b * HID + k] = acc;
  }
}

// ==== scores: 256x256 tile, BK=64, 8 waves, counted-vmcnt pipeline ====
__launch_bounds__(512, 2)
__global__ void scores8_kernel(const unsigned short* __restrict__ encb,
                               const unsigned short* __restrict__ W2b,
                               const float* __restrict__ dh, const float* __restrict__ v,
                               float* __restrict__ scores) {
  __shared__ __align__(16) unsigned short sA[2][16384];  // [dbuf][256 rows * 64 k]
  __shared__ __align__(16) unsigned short sB[2][16384];
  __shared__ float dh_s[256];
  __shared__ float v_s[256];

  int bid = blockIdx.x;
  int wg = (bid & 7) * 64 + (bid >> 3);
  int mt = wg >> 2, nt = wg & 3;
  int m0 = mt * 256, n0 = nt * 256;

  int t = threadIdx.x;
  int wid = t >> 6, l = t & 63;
  int wr = wid >> 2, wc = wid & 3;     // 2 M-waves x 4 N-waves
  int fr = l & 15, co = (l >> 4) * 8;

  const unsigned short* pa0;
  const unsigned short* pb0;
  int do0 = wid * 512;
  {
    int base = wid * 1024 + l * 16;                 // byte offset in chunk 0
    int srel = base ^ (((base >> 8) & 3) << 4);     // involution
    int row = srel >> 7, colE = (srel >> 1) & 63;
    pa0 = encb + (size_t)(m0 + row) * HID + colE;
    pb0 = W2b + (size_t)(n0 + row) * HID + colE;
  }

  f32x4 acc[8][4];
#pragma unroll
  for (int i = 0; i < 8; i++)
#pragma unroll
    for (int j = 0; j < 4; j++) acc[i][j] = (f32x4){0.f, 0.f, 0.f, 0.f};

#define SC_STAGE(T, d)                                                         \
  do {                                                                         \
    int k0_ = (T) * 64;                                                        \
    gload16(pa0 + k0_,          &sA[d][do0]);                                  \
    gload16(pa0 + 65536 + k0_,  &sA[d][do0 + 4096]);                           \
    gload16(pa0 + 131072 + k0_, &sA[d][do0 + 8192]);                           \
    gload16(pa0 + 196608 + k0_, &sA[d][do0 + 12288]);                          \
    gload16(pb0 + k0_,          &sB[d][do0]);                                  \
    gload16(pb0 + 65536 + k0_,  &sB[d][do0 + 4096]);                           \
    gload16(pb0 + 131072 + k0_, &sB[d][do0 + 8192]);                           \
    gload16(pb0 + 196608 + k0_, &sB[d][do0 + 12288]);                          \
  } while (0)

  SC_STAGE(0, 0);
  SC_STAGE(1, 1);

#define LDF(Mat, row, ks) \
  (*(const bf16x8*)&Mat[(row) * 64 + (((ks) * 32 + co) ^ ((((row) >> 1) & 3) << 3))])

  for (int T = 0; T < 16; ++T) {
    int d = T & 1;
    if (T == 15) asm volatile("s_waitcnt vmcnt(0)" ::: "memory");
    else         asm volatile("s_waitcnt vmcnt(8)" ::: "memory");
    asm volatile("s_barrier" ::: "memory");
    const unsigned short* A = sA[d];
    const unsigned short* B = sB[d];
    bf16x8 a[4][2], b[4][2];
#pragma unroll
    for (int jj = 0; jj < 4; ++jj)
#pragma unroll
      for (int ks = 0; ks < 2; ++ks)
        b[jj][ks] = LDF(B, wc * 64 + jj * 16 + fr, ks);
#pragma unroll
    for (int ii = 0; ii < 4; ++ii)
#pragma unroll
      for (int ks = 0; ks < 2; ++ks)
        a[ii][ks] = LDF(A, wr * 128 + ii * 16 + fr, ks);
    __builtin_amdgcn_s_setprio(1);
#pragma unroll
    for (int ii = 0; ii < 4; ++ii)
#pragma unroll
      for (int jj = 0; jj < 2; ++jj)
#pragma unroll
        for (int ks = 0; ks < 2; ++ks)
          acc[ii][jj] = __builtin_amdgcn_mfma_f32_16x16x32_bf16(a[ii][ks], b[jj][ks], acc[ii][jj], 0, 0, 0);
    __builtin_amdgcn_s_setprio(0);
    __builtin_amdgcn_s_setprio(1);
#pragma unroll
    for (int ii = 0; ii < 4; ++ii)
#pragma unroll
      for (int jj = 2; jj < 4; ++jj)
#pragma unroll
        for (int ks = 0; ks < 2; ++ks)
          acc[ii][jj] = __builtin_amdgcn_mfma_f32_16x16x32_bf16(a[ii][ks], b[jj][ks], acc[ii][jj], 0, 0, 0);
    __builtin_amdgcn_s_setprio(0);
#pragma unroll
    for (int ii = 0; ii < 4; ++ii)
#pragma unroll
      for (int ks = 0; ks < 2; ++ks)
        a[ii][ks] = LDF(A, wr * 128 + 64 + ii * 16 + fr, ks);
    __builtin_amdgcn_s_setprio(1);
#pragma unroll
    for (int ii = 0; ii < 4; ++ii)
#pragma unroll
      for (int jj = 2; jj < 4; ++jj)
#pragma unroll
        for (int ks = 0; ks < 2; ++ks)
          acc[4 + ii][jj] = __builtin_amdgcn_mfma_f32_16x16x32_bf16(a[ii][ks], b[jj][ks], acc[4 + ii][jj], 0, 0, 0);
    __builtin_amdgcn_s_setprio(0);
    __builtin_amdgcn_s_setprio(1);
#pragma unroll
    for (int ii = 0; ii < 4; ++ii)
#pragma unroll
      for (int jj = 0; jj < 2; ++jj)
#pragma unroll
        for (int ks = 0; ks < 2; ++ks)
          acc[4 + ii][jj] = __builtin_amdgcn_mfma_f32_16x16x32_bf16(a[ii][ks], b[jj][ks], acc[4 + ii][jj], 0, 0, 0);
    __builtin_amdgcn_s_setprio(0);
    asm volatile("s_barrier" ::: "memory");   // all reads of dbuf d done
    if (T < 14) SC_STAGE(T + 2, d);           // prefetch tile T+2 into dbuf d
  }
#undef LDF
#undef SC_STAGE

  // epilogue: partial scores over this 256-wide n-tile (fast_tanh)
  int b = m0 >> 9;
  if (t < 256) { dh_s[t] = dh[b * HID + n0 + t]; v_s[t] = v[n0 + t]; }
  __syncthreads();
  float sp[32];
#pragma unroll
  for (int q = 0; q < 32; ++q) sp[q] = 0.f;
#pragma unroll
  for (int ii = 0; ii < 8; ++ii)
#pragma unroll
    for (int jj = 0; jj < 4; ++jj) {
      int nl = wc * 64 + jj * 16 + fr;
      float dv = dh_s[nl], vv = v_s[nl];
#pragma unroll
      for (int r = 0; r < 4; ++r)
        sp[ii * 4 + r] += fast_tanh(dv + acc[ii][jj][r]) * vv;
    }
#pragma unroll
  for (int q = 0; q < 32; ++q) {
    float x = sp[q];
    x += __shfl_xor(x, 1);
    x += __shfl_xor(x, 2);
    x += __shfl_xor(x, 4);
    x += __shfl_xor(x, 8);
    sp[q] = x;
  }
  if (fr == 0) {
    int rbase = m0 + wr * 128 + (l >> 4) * 4;
#pragma unroll
    for (int ii = 0; ii < 8; ++ii)
#pragma unroll
      for (int r = 0; r < 4; ++r)
        atomicAdd(&scores[rbase + ii * 16 + r], sp[ii * 4 + r]);
  }
}

// ---------------- softmax over S per batch row ----------------
__global__ void softmax_kernel(const float* __restrict__ scores, float* __restrict__ attn) {
  __shared__ float red[8];
  int b = blockIdx.x, t = threadIdx.x;  // 512 threads
  float x = scores[b * SEQ + t];
  float m = x;
  for (int d = 1; d < 64; d <<= 1) m = fmaxf(m, __shfl_xor(m, d));
  if ((t & 63) == 0) red[t >> 6] = m;
  __syncthreads();
  float bm = red[0];
#pragma unroll
  for (int i = 1; i < 8; i++) bm = fmaxf(bm, red[i]);
  float e = expf(x - bm);
  float s = e;
  for (int d = 1; d < 64; d <<= 1) s += __shfl_xor(s, d);
  __syncthreads();
  if ((t & 63) == 0) red[t >> 6] = s;
  __syncthreads();
  float bs = 0.f;
#pragma unroll
  for (int i = 0; i < 8; i++) bs += red[i];
  attn[b * SEQ + t] = e / bs;
}

// ------- context: bf16 enc, 16B/lane; ctx[b,h] = sum_s attn[b,s]*enc[b,s,h] -------
__global__ void context2_kernel(const unsigned short* __restrict__ encb,
                                const float* __restrict__ attn, float* __restrict__ ctx) {
  __shared__ float a_s[64];
  int b = blockIdx.y, s0 = blockIdx.x * 64, t = threadIdx.x;
  if (t < 64) a_s[t] = attn[b * SEQ + s0 + t];
  __syncthreads();
  int hg = (t & 127) * 8, sg = (t >> 7) * 32;  // 128 h-threads x 2 s-groups
  float a0 = 0.f, a1 = 0.f, a2 = 0.f, a3 = 0.f, a4 = 0.f, a5 = 0.f, a6 = 0.f, a7 = 0.f;
  const unsigned short* base = encb + ((size_t)b * SEQ + s0 + sg) * HID + hg;
  for (int s = 0; s < 32; s++) {
    uint4 ev = *(const uint4*)(base + (size_t)s * HID);
    float a = a_s[sg + s];
    a0 += a * bf2f(ev.x & 0xffffu); a1 += a * bf2f(ev.x >> 16);
    a2 += a * bf2f(ev.y & 0xffffu); a3 += a * bf2f(ev.y >> 16);
    a4 += a * bf2f(ev.z & 0xffffu); a5 += a * bf2f(ev.z >> 16);
    a6 += a * bf2f(ev.w & 0xffffu); a7 += a * bf2f(ev.w >> 16);
  }
  atomicAdd(&ctx[b * HID + hg + 0], a0);
  atomicAdd(&ctx[b * HID + hg + 1], a1);
  atomicAdd(&ctx[b * HID + hg + 2], a2);
  atomicAdd(&ctx[b * HID + hg + 3], a3);
  atomicAdd(&ctx[b * HID + hg + 4], a4);
  atomicAdd(&ctx[b * HID + hg + 5], a5);
  atomicAdd(&ctx[b * HID + hg + 6], a6);
  atomicAdd(&ctx[b * HID + hg + 7], a7);
}

// ==== gates via MFMA: gpart[kz] = x @ W[:, kz*320:+320]^T  (M=64, N=4096) ====
__launch_bounds__(256)
__global__ void gates8p_kernel(const int* __restrict__ tok, const float* __restrict__ emb,
                               const float* __restrict__ ctx, const float* __restrict__ h0,
                               const float* __restrict__ W_ih, const float* __restrict__ W_hh,
                               float* __restrict__ gpart) {
  __shared__ __align__(16) unsigned short lA[64 * 40];
  __shared__ __align__(16) unsigned short lB[128 * 40];
  int n0 = blockIdx.x * 128, kz = blockIdx.y;   // 32 n-blocks x 8 K-slices
  int kbase = kz * 320;
  int t = threadIdx.x, w = t >> 6, l = t & 63;
  f32x4 acc[4][2];
#pragma unroll
  for (int i = 0; i < 4; i++)
#pragma unroll
    for (int j = 0; j < 2; j++) acc[i][j] = (f32x4){0.f, 0.f, 0.f, 0.f};
  int rowA = t >> 2, qA = (t & 3) * 8;   // 64 rows x 4 quads of 8
  int rowB = t >> 1, hB = t & 1;         // 128 rows x 2 halves of 16
  int tkA = tok[rowA];

  for (int kt = 0; kt < 10; kt++) {
    int k0 = kbase + kt * 32;
    {  // A stage (segments never cross 512/1536)
      int kg = k0 + qA;
      const float* src;
      if (kg < 512)        src = emb + (size_t)tkA * EMBED + kg;
      else if (kg < 1536)  src = ctx + rowA * HID + (kg - 512);
      else                 src = h0 + rowA * HID + (kg - 1536);
      float4 f0 = *(const float4*)src;
      float4 f1 = *(const float4*)(src + 4);
      union { unsigned short us[8]; uint4 u; } p;
      p.us[0]=f2bf(f0.x); p.us[1]=f2bf(f0.y); p.us[2]=f2bf(f0.z); p.us[3]=f2bf(f0.w);
      p.us[4]=f2bf(f1.x); p.us[5]=f2bf(f1.y); p.us[6]=f2bf(f1.z); p.us[7]=f2bf(f1.w);
      *(uint4*)&lA[rowA * 40 + qA] = p.u;
    }
    {  // B stage (16-seg never crosses 1536)
      int kg = k0 + hB * 16;
      const float* src = (kg < 1536) ? (W_ih + (size_t)(n0 + rowB) * 1536 + kg)
                                     : (W_hh + (size_t)(n0 + rowB) * 1024 + (kg - 1536));
      stage16(src, &lB[rowB * 40 + hB * 16]);
    }
    __syncthreads();
    bf16x8 af[4], bv[2];
    int co = (l >> 4) * 8;
#pragma unroll
    for (int i = 0; i < 4; i++) af[i] = *(const bf16x8*)&lA[(i * 16 + (l & 15)) * 40 + co];
#pragma unroll
    for (int j = 0; j < 2; j++) bv[j] = *(const bf16x8*)&lB[(w * 32 + j * 16 + (l & 15)) * 40 + co];
#pragma unroll
    for (int i = 0; i < 4; i++)
#pragma unroll
      for (int j = 0; j < 2; j++)
        acc[i][j] = __builtin_amdgcn_mfma_f32_16x16x32_bf16(af[i], bv[j], acc[i][j], 0, 0, 0);
    __syncthreads();
  }
#pragma unroll
  for (int i = 0; i < 4; i++)
#pragma unroll
    for (int j = 0; j < 2; j++) {
      int n = n0 + w * 32 + j * 16 + (l & 15);
#pragma unroll
      for (int r = 0; r < 4; r++) {
        int m = i * 16 + (l >> 4) * 4 + r;
        gpart[(size_t)kz * 262144 + (size_t)m * 4096 + n] = acc[i][j][r];
      }
    }
}

// ------- LSTM pointwise (fused 8-plane gate combine) -> h1, c1 -------
__global__ void lstm_kernel(const float* __restrict__ gpart, const float* __restrict__ b_ih,
                            const float* __restrict__ b_hh, const float* __restrict__ c0,
                            float* __restrict__ out) {
  int b = blockIdx.y;
  int hh = blockIdx.x * 256 + threadIdx.x;
  float gi = b_ih[hh]        + b_hh[hh];
  float gf = b_ih[1024 + hh] + b_hh[1024 + hh];
  float gg = b_ih[2048 + hh] + b_hh[2048 + hh];
  float go = b_ih[3072 + hh] + b_hh[3072 + hh];
#pragma unroll
  for (int kz = 0; kz < 8; kz++) {
    const float* g = gpart + (size_t)kz * 262144 + (size_t)b * 4096;
    gi += g[hh];
    gf += g[1024 + hh];
    gg += g[2048 + hh];
    go += g[3072 + hh];
  }
  float si = 1.f / (1.f + expf(-gi));
  float sf = 1.f / (1.f + expf(-gf));
  float so = 1.f / (1.f + expf(-go));
  float c1 = sf * c0[b * HID + hh] + si * tanhf(gg);
  float h1 = so * tanhf(c1);
  out[OUT_H1 + b * HID + hh] = h1;
  out[OUT_C1 + b * HID + hh] = c1;
}

// ---- fc: K-split x2, partial planes (r7-proven single-buffer version) ----
__launch_bounds__(256)
__global__ void fc2p_kernel(const float* __restrict__ h1, const float* __restrict__ ctx,
                            const float* __restrict__ fcW, float* __restrict__ part) {
  __shared__ __align__(16) unsigned short lA[64 * 40];
  __shared__ __align__(16) unsigned short lB[128 * 40];
  int n0 = blockIdx.x * 128, kz = blockIdx.y;
  const float* A = kz ? ctx : h1;
  int t = threadIdx.x, w = t >> 6, l = t & 63;
  f32x4 acc[4][2];
#pragma unroll
  for (int i = 0; i < 4; i++)
#pragma unroll
    for (int j = 0; j < 2; j++) acc[i][j] = (f32x4){0.f, 0.f, 0.f, 0.f};
  int rowA = t >> 2, qA = (t & 3) * 8;
  int rowB = t >> 1, hB = t & 1;

  for (int kt = 0; kt < 32; kt++) {
    int k0 = kt * 32;
    {
      const float* src = A + rowA * HID + k0 + qA;
      float4 f0 = *(const float4*)src;
      float4 f1 = *(const float4*)(src + 4);
      union { unsigned short us[8]; uint4 u; } p;
      p.us[0]=f2bf(f0.x); p.us[1]=f2bf(f0.y); p.us[2]=f2bf(f0.z); p.us[3]=f2bf(f0.w);
      p.us[4]=f2bf(f1.x); p.us[5]=f2bf(f1.y); p.us[6]=f2bf(f1.z); p.us[7]=f2bf(f1.w);
      *(uint4*)&lA[rowA * 40 + qA] = p.u;
    }
    stage16(fcW + (size_t)(n0 + rowB) * 2048 + kz * 1024 + k0 + hB * 16,
            &lB[rowB * 40 + hB * 16]);
    __syncthreads();
    bf16x8 af[4], bv[2];
    int co = (l >> 4) * 8;
#pragma unroll
    for (int i = 0; i < 4; i++) af[i] = *(const bf16x8*)&lA[(i * 16 + (l & 15)) * 40 + co];
#pragma unroll
    for (int j = 0; j < 2; j++) bv[j] = *(const bf16x8*)&lB[(w * 32 + j * 16 + (l & 15)) * 40 + co];
#pragma unroll
    for (int i = 0; i < 4; i++)
#pragma unroll
      for (int j = 0; j < 2; j++)
        acc[i][j] = __builtin_amdgcn_mfma_f32_16x16x32_bf16(af[i], bv[j], acc[i][j], 0, 0, 0);
    __syncthreads();
  }
#pragma unroll
  for (int i = 0; i < 4; i++)
#pragma unroll
    for (int j = 0; j < 2; j++) {
      int n = n0 + w * 32 + j * 16 + (l & 15);
#pragma unroll
      for (int r = 0; r < 4; r++) {
        int m = i * 16 + (l >> 4) * 4 + r;
        part[(size_t)kz * 2048000 + (size_t)m * VOCAB + n] = acc[i][j][r];
      }
    }
}

// ---- combine: pred = part0 + part1 + bias, float4 ----
__global__ void fc_combine_kernel(const float* __restrict__ part,
                                  const float* __restrict__ fcb, float* __restrict__ pred) {
  int i = blockIdx.x * 256 + threadIdx.x;   // 2000*256 = 512000 float4s
  int m = i / 8000, n4 = i % 8000;
  size_t e = (size_t)m * VOCAB + n4 * 4;
  float4 p0 = *(const float4*)(part + e);
  float4 p1 = *(const float4*)(part + 2048000 + e);
  float4 bb = *(const float4*)(fcb + n4 * 4);
  float4 o;
  o.x = p0.x + p1.x + bb.x;
  o.y = p0.y + p1.y + bb.y;
  o.z = p0.z + p1.z + bb.z;
  o.w = p0.w + p1.w + bb.w;
  *(float4*)(pred + e) = o;
}

extern "C" void kernel_launch(void* const* d_in, const int* in_sizes, int n_in,
                              void* d_out, int out_size, void* d_ws, size_t ws_size,
                              hipStream_t stream) {
  const int*   tok  = (const int*)d_in[0];
  const float* h    = (const float*)d_in[1];
  const float* c    = (const float*)d_in[2];
  const float* enc  = (const float*)d_in[3];
  const float* emb  = (const float*)d_in[4];
  const float* W1   = (const float*)d_in[5];
  const float* W2   = (const float*)d_in[6];
  const float* v    = (const float*)d_in[7];
  const float* W_ih = (const float*)d_in[8];
  const float* W_hh = (const float*)d_in[9];
  const float* b_ih = (const float*)d_in[10];
  const float* b_hh = (const float*)d_in[11];
  const float* fcW  = (const float*)d_in[12];
  const float* fcb  = (const float*)d_in[13];
  float* out = (float*)d_out;

  float* wsf    = (float*)d_ws;
  float* scores = wsf;             // 32768
  float* ctx    = wsf + 32768;     // 65536   (zeroed with scores: 98304 total)
  float* dh     = wsf + 98304;     // 65536
  float* gpart  = wsf + 163840;    // 8*262144 = 2097152
  float* part   = wsf + 2260992;   // 2*2048000 = 4096000
  unsigned short* encb = (unsigned short*)(wsf + 6356992);   // 33,554,432 bf16
  unsigned short* W2b  = encb + (size_t)BATCH * SEQ * HID;   //  1,048,576 bf16

  prep_kernel<<<2912, 256, 0, stream>>>(enc, encb, W2, W2b, wsf, h, W1, dh);
  scores8_kernel<<<512, 512, 0, stream>>>(encb, W2b, dh, v, scores);
  softmax_kernel<<<64, 512, 0, stream>>>(scores, out + OUT_ATTN);
  context2_kernel<<<dim3(8, 64), 256, 0, stream>>>(encb, out + OUT_ATTN, ctx);
  gates8p_kernel<<<dim3(32, 8), 256, 0, stream>>>(tok, emb, ctx, h, W_ih, W_hh, gpart);
  lstm_kernel<<<dim3(4, 64), 256, 0, stream>>>(gpart, b_ih, b_hh, c, out);
  fc2p_kernel<<<dim3(250, 2), 256, 0, stream>>>(out + OUT_H1, ctx, fcW, part);
  fc_combine_kernel<<<2000, 256, 0, stream>>>(part, fcb, out);
}

// Round 10
// 298.341 us; speedup vs baseline: 1.1613x; 1.1613x over previous
//
#include <hip/hip_runtime.h>
#include <math.h>

#define VOCAB 32000
#define EMBED 512
#define HID   1024
#define BATCH 64
#define SEQ   512

// d_out layout (floats): pred[64*32000]=0 .. 2048000 ; h1 @2048000 ; c1 @2113536 ; attn @2179072
#define OUT_H1   2048000
#define OUT_C1   2113536
#define OUT_ATTN 2179072

typedef __bf16 bf16x8 __attribute__((ext_vector_type(8)));
typedef float  f32x4  __attribute__((ext_vector_type(4)));

__device__ __forceinline__ unsigned short f2bf(float f) {
  unsigned int u = __builtin_bit_cast(unsigned int, f);
  u += 0x7fffu + ((u >> 16) & 1u);   // round-to-nearest-even
  return (unsigned short)(u >> 16);
}
__device__ __forceinline__ float bf2f(unsigned int u) {
  return __builtin_bit_cast(float, u << 16);
}

// fast tanh: (e^{2x}-1)/(e^{2x}+1) via hw exp2; clamp avoids inf/inf
__device__ __forceinline__ float fast_tanh(float x) {
  float cx = fminf(fmaxf(x, -15.f), 15.f);
  float t = __builtin_amdgcn_exp2f(cx * 2.8853900817779268f);  // e^{2x}
  return (t - 1.f) / (t + 1.f);
}

// async 16B/lane global->LDS; lds ptr must be wave-uniform (HW: base + lane*16)
__device__ __forceinline__ void gload16(const unsigned short* g, unsigned short* l) {
  __builtin_amdgcn_global_load_lds(
      (const __attribute__((address_space(1))) void*)g,
      (__attribute__((address_space(3))) void*)l, 16, 0, 0);
}

// 16 f32 -> 16 bf16 (RNE bit-trick), 32B to LDS
__device__ __forceinline__ void stage16(const float* __restrict__ src, unsigned short* dst) {
  float4 f0 = *(const float4*)(src + 0);
  float4 f1 = *(const float4*)(src + 4);
  float4 f2 = *(const float4*)(src + 8);
  float4 f3 = *(const float4*)(src + 12);
  union { unsigned short us[16]; uint4 u4[2]; } p;
  p.us[0]=f2bf(f0.x);  p.us[1]=f2bf(f0.y);  p.us[2]=f2bf(f0.z);  p.us[3]=f2bf(f0.w);
  p.us[4]=f2bf(f1.x);  p.us[5]=f2bf(f1.y);  p.us[6]=f2bf(f1.z);  p.us[7]=f2bf(f1.w);
  p.us[8]=f2bf(f2.x);  p.us[9]=f2bf(f2.y);  p.us[10]=f2bf(f2.z); p.us[11]=f2bf(f2.w);
  p.us[12]=f2bf(f3.x); p.us[13]=f2bf(f3.y); p.us[14]=f2bf(f3.z); p.us[15]=f2bf(f3.w);
  *(uint4*)(dst + 0) = p.u4[0];
  *(uint4*)(dst + 8) = p.u4[1];
}

// ---- zero scores+ctx (atomic targets): 98304 floats ----
__global__ void zero_ws_kernel(float* __restrict__ p) {
  int i = blockIdx.x * 256 + threadIdx.x;     // 96*256 threads * 4 floats = 98304
  *(float4*)(p + (size_t)i * 4) = (float4){0.f, 0.f, 0.f, 0.f};
}

// ------------- f32 -> bf16 bulk convert (grid-stride, 8 elems/thread/iter) -------------
__global__ void f2bf_kernel(const float* __restrict__ src, unsigned short* __restrict__ dst,
                            int n8) {
  int i = blockIdx.x * blockDim.x + threadIdx.x;
  int stride = gridDim.x * blockDim.x;
  for (; i < n8; i += stride) {
    const float* s = src + (size_t)i * 8;
    float4 f0 = *(const float4*)s;
    float4 f1 = *(const float4*)(s + 4);
    union { unsigned short us[8]; uint4 u; } p;
    p.us[0]=f2bf(f0.x); p.us[1]=f2bf(f0.y); p.us[2]=f2bf(f0.z); p.us[3]=f2bf(f0.w);
    p.us[4]=f2bf(f1.x); p.us[5]=f2bf(f1.y); p.us[6]=f2bf(f1.z); p.us[7]=f2bf(f1.w);
    *(uint4*)(dst + (size_t)i * 8) = p.u;
  }
}

// ---------------- dh = h0 @ W1^T  (64x1024, K=1024) ----------------
__global__ void dh_kernel(const float* __restrict__ h0, const float* __restrict__ W1,
                          float* __restrict__ dh) {
  __shared__ float hs[HID];
  int b = blockIdx.y, t = threadIdx.x;
  for (int i = t; i < HID; i += 256) hs[i] = h0[b * HID + i];
  __syncthreads();
  int k = blockIdx.x * 256 + t;
  const float* w = W1 + (size_t)k * HID;
  float acc = 0.f;
  for (int hh = 0; hh < HID; hh += 4) {
    float4 wv = *(const float4*)(w + hh);
    float4 hv = *(const float4*)(hs + hh);
    acc += wv.x * hv.x + wv.y * hv.y + wv.z * hv.z + wv.w * hv.w;
  }
  dh[b * HID + k] = acc;
}

// ==== scores: 256x256 tile, BK=64, 8 waves, counted-vmcnt pipeline ====
__launch_bounds__(512, 2)
__global__ void scores8_kernel(const unsigned short* __restrict__ encb,
                               const unsigned short* __restrict__ W2b,
                               const float* __restrict__ dh, const float* __restrict__ v,
                               float* __restrict__ scores) {
  __shared__ __align__(16) unsigned short sA[2][16384];  // [dbuf][256 rows * 64 k]
  __shared__ __align__(16) unsigned short sB[2][16384];
  __shared__ float dh_s[256];
  __shared__ float v_s[256];

  int bid = blockIdx.x;
  int wg = (bid & 7) * 64 + (bid >> 3);
  int mt = wg >> 2, nt = wg & 3;
  int m0 = mt * 256, n0 = nt * 256;

  int t = threadIdx.x;
  int wid = t >> 6, l = t & 63;
  int wr = wid >> 2, wc = wid & 3;     // 2 M-waves x 4 N-waves
  int fr = l & 15, co = (l >> 4) * 8;

  const unsigned short* pa0;
  const unsigned short* pb0;
  int do0 = wid * 512;
  {
    int base = wid * 1024 + l * 16;                 // byte offset in chunk 0
    int srel = base ^ (((base >> 8) & 3) << 4);     // involution
    int row = srel >> 7, colE = (srel >> 1) & 63;
    pa0 = encb + (size_t)(m0 + row) * HID + colE;
    pb0 = W2b + (size_t)(n0 + row) * HID + colE;
  }

  f32x4 acc[8][4];
#pragma unroll
  for (int i = 0; i < 8; i++)
#pragma unroll
    for (int j = 0; j < 4; j++) acc[i][j] = (f32x4){0.f, 0.f, 0.f, 0.f};

#define SC_STAGE(T, d)                                                         \
  do {                                                                         \
    int k0_ = (T) * 64;                                                        \
    gload16(pa0 + k0_,          &sA[d][do0]);                                  \
    gload16(pa0 + 65536 + k0_,  &sA[d][do0 + 4096]);                           \
    gload16(pa0 + 131072 + k0_, &sA[d][do0 + 8192]);                           \
    gload16(pa0 + 196608 + k0_, &sA[d][do0 + 12288]);                          \
    gload16(pb0 + k0_,          &sB[d][do0]);                                  \
    gload16(pb0 + 65536 + k0_,  &sB[d][do0 + 4096]);                           \
    gload16(pb0 + 131072 + k0_, &sB[d][do0 + 8192]);                           \
    gload16(pb0 + 196608 + k0_, &sB[d][do0 + 12288]);                          \
  } while (0)

  SC_STAGE(0, 0);
  SC_STAGE(1, 1);

#define LDF(Mat, row, ks) \
  (*(const bf16x8*)&Mat[(row) * 64 + (((ks) * 32 + co) ^ ((((row) >> 1) & 3) << 3))])

  for (int T = 0; T < 16; ++T) {
    int d = T & 1;
    if (T == 15) asm volatile("s_waitcnt vmcnt(0)" ::: "memory");
    else         asm volatile("s_waitcnt vmcnt(8)" ::: "memory");
    asm volatile("s_barrier" ::: "memory");
    const unsigned short* A = sA[d];
    const unsigned short* B = sB[d];
    bf16x8 a[4][2], b[4][2];
#pragma unroll
    for (int jj = 0; jj < 4; ++jj)
#pragma unroll
      for (int ks = 0; ks < 2; ++ks)
        b[jj][ks] = LDF(B, wc * 64 + jj * 16 + fr, ks);
#pragma unroll
    for (int ii = 0; ii < 4; ++ii)
#pragma unroll
      for (int ks = 0; ks < 2; ++ks)
        a[ii][ks] = LDF(A, wr * 128 + ii * 16 + fr, ks);
    __builtin_amdgcn_s_setprio(1);
#pragma unroll
    for (int ii = 0; ii < 4; ++ii)
#pragma unroll
      for (int jj = 0; jj < 2; ++jj)
#pragma unroll
        for (int ks = 0; ks < 2; ++ks)
          acc[ii][jj] = __builtin_amdgcn_mfma_f32_16x16x32_bf16(a[ii][ks], b[jj][ks], acc[ii][jj], 0, 0, 0);
    __builtin_amdgcn_s_setprio(0);
    __builtin_amdgcn_s_setprio(1);
#pragma unroll
    for (int ii = 0; ii < 4; ++ii)
#pragma unroll
      for (int jj = 2; jj < 4; ++jj)
#pragma unroll
        for (int ks = 0; ks < 2; ++ks)
          acc[ii][jj] = __builtin_amdgcn_mfma_f32_16x16x32_bf16(a[ii][ks], b[jj][ks], acc[ii][jj], 0, 0, 0);
    __builtin_amdgcn_s_setprio(0);
#pragma unroll
    for (int ii = 0; ii < 4; ++ii)
#pragma unroll
      for (int ks = 0; ks < 2; ++ks)
        a[ii][ks] = LDF(A, wr * 128 + 64 + ii * 16 + fr, ks);
    __builtin_amdgcn_s_setprio(1);
#pragma unroll
    for (int ii = 0; ii < 4; ++ii)
#pragma unroll
      for (int jj = 2; jj < 4; ++jj)
#pragma unroll
        for (int ks = 0; ks < 2; ++ks)
          acc[4 + ii][jj] = __builtin_amdgcn_mfma_f32_16x16x32_bf16(a[ii][ks], b[jj][ks], acc[4 + ii][jj], 0, 0, 0);
    __builtin_amdgcn_s_setprio(0);
    __builtin_amdgcn_s_setprio(1);
#pragma unroll
    for (int ii = 0; ii < 4; ++ii)
#pragma unroll
      for (int jj = 0; jj < 2; ++jj)
#pragma unroll
        for (int ks = 0; ks < 2; ++ks)
          acc[4 + ii][jj] = __builtin_amdgcn_mfma_f32_16x16x32_bf16(a[ii][ks], b[jj][ks], acc[4 + ii][jj], 0, 0, 0);
    __builtin_amdgcn_s_setprio(0);
    asm volatile("s_barrier" ::: "memory");   // all reads of dbuf d done
    if (T < 14) SC_STAGE(T + 2, d);           // prefetch tile T+2 into dbuf d
  }
#undef LDF
#undef SC_STAGE

  // epilogue: partial scores over this 256-wide n-tile (fast_tanh)
  int b = m0 >> 9;
  if (t < 256) { dh_s[t] = dh[b * HID + n0 + t]; v_s[t] = v[n0 + t]; }
  __syncthreads();
  float sp[32];
#pragma unroll
  for (int q = 0; q < 32; ++q) sp[q] = 0.f;
#pragma unroll
  for (int ii = 0; ii < 8; ++ii)
#pragma unroll
    for (int jj = 0; jj < 4; ++jj) {
      int nl = wc * 64 + jj * 16 + fr;
      float dv = dh_s[nl], vv = v_s[nl];
#pragma unroll
      for (int r = 0; r < 4; ++r)
        sp[ii * 4 + r] += fast_tanh(dv + acc[ii][jj][r]) * vv;
    }
#pragma unroll
  for (int q = 0; q < 32; ++q) {
    float x = sp[q];
    x += __shfl_xor(x, 1);
    x += __shfl_xor(x, 2);
    x += __shfl_xor(x, 4);
    x += __shfl_xor(x, 8);
    sp[q] = x;
  }
  if (fr == 0) {
    int rbase = m0 + wr * 128 + (l >> 4) * 4;
#pragma unroll
    for (int ii = 0; ii < 8; ++ii)
#pragma unroll
      for (int r = 0; r < 4; ++r)
        atomicAdd(&scores[rbase + ii * 16 + r], sp[ii * 4 + r]);
  }
}

// ---------------- softmax over S per batch row ----------------
__global__ void softmax_kernel(const float* __restrict__ scores, float* __restrict__ attn) {
  __shared__ float red[8];
  int b = blockIdx.x, t = threadIdx.x;  // 512 threads
  float x = scores[b * SEQ + t];
  float m = x;
  for (int d = 1; d < 64; d <<= 1) m = fmaxf(m, __shfl_xor(m, d));
  if ((t & 63) == 0) red[t >> 6] = m;
  __syncthreads();
  float bm = red[0];
#pragma unroll
  for (int i = 1; i < 8; i++) bm = fmaxf(bm, red[i]);
  float e = expf(x - bm);
  float s = e;
  for (int d = 1; d < 64; d <<= 1) s += __shfl_xor(s, d);
  __syncthreads();
  if ((t & 63) == 0) red[t >> 6] = s;
  __syncthreads();
  float bs = 0.f;
#pragma unroll
  for (int i = 0; i < 8; i++) bs += red[i];
  attn[b * SEQ + t] = e / bs;
}

// ------- context: bf16 enc, 16B/lane; ctx[b,h] = sum_s attn[b,s]*enc[b,s,h] -------
__global__ void context2_kernel(const unsigned short* __restrict__ encb,
                                const float* __restrict__ attn, float* __restrict__ ctx) {
  __shared__ float a_s[64];
  int b = blockIdx.y, s0 = blockIdx.x * 64, t = threadIdx.x;
  if (t < 64) a_s[t] = attn[b * SEQ + s0 + t];
  __syncthreads();
  int hg = (t & 127) * 8, sg = (t >> 7) * 32;  // 128 h-threads x 2 s-groups
  float a0 = 0.f, a1 = 0.f, a2 = 0.f, a3 = 0.f, a4 = 0.f, a5 = 0.f, a6 = 0.f, a7 = 0.f;
  const unsigned short* base = encb + ((size_t)b * SEQ + s0 + sg) * HID + hg;
  for (int s = 0; s < 32; s++) {
    uint4 ev = *(const uint4*)(base + (size_t)s * HID);
    float a = a_s[sg + s];
    a0 += a * bf2f(ev.x & 0xffffu); a1 += a * bf2f(ev.x >> 16);
    a2 += a * bf2f(ev.y & 0xffffu); a3 += a * bf2f(ev.y >> 16);
    a4 += a * bf2f(ev.z & 0xffffu); a5 += a * bf2f(ev.z >> 16);
    a6 += a * bf2f(ev.w & 0xffffu); a7 += a * bf2f(ev.w >> 16);
  }
  atomicAdd(&ctx[b * HID + hg + 0], a0);
  atomicAdd(&ctx[b * HID + hg + 1], a1);
  atomicAdd(&ctx[b * HID + hg + 2], a2);
  atomicAdd(&ctx[b * HID + hg + 3], a3);
  atomicAdd(&ctx[b * HID + hg + 4], a4);
  atomicAdd(&ctx[b * HID + hg + 5], a5);
  atomicAdd(&ctx[b * HID + hg + 6], a6);
  atomicAdd(&ctx[b * HID + hg + 7], a7);
}

// ==== gates via MFMA: gpart[kz] = x @ W[:, kz*320:+320]^T  (M=64, N=4096) ====
__launch_bounds__(256)
__global__ void gates8p_kernel(const int* __restrict__ tok, const float* __restrict__ emb,
                               const float* __restrict__ ctx, const float* __restrict__ h0,
                               const float* __restrict__ W_ih, const float* __restrict__ W_hh,
                               float* __restrict__ gpart) {
  __shared__ __align__(16) unsigned short lA[64 * 40];
  __shared__ __align__(16) unsigned short lB[128 * 40];
  int n0 = blockIdx.x * 128, kz = blockIdx.y;   // 32 n-blocks x 8 K-slices
  int kbase = kz * 320;
  int t = threadIdx.x, w = t >> 6, l = t & 63;
  f32x4 acc[4][2];
#pragma unroll
  for (int i = 0; i < 4; i++)
#pragma unroll
    for (int j = 0; j < 2; j++) acc[i][j] = (f32x4){0.f, 0.f, 0.f, 0.f};
  int rowA = t >> 2, qA = (t & 3) * 8;   // 64 rows x 4 quads of 8
  int rowB = t >> 1, hB = t & 1;         // 128 rows x 2 halves of 16
  int tkA = tok[rowA];

  for (int kt = 0; kt < 10; kt++) {
    int k0 = kbase + kt * 32;
    {  // A stage (segments never cross 512/1536)
      int kg = k0 + qA;
      const float* src;
      if (kg < 512)        src = emb + (size_t)tkA * EMBED + kg;
      else if (kg < 1536)  src = ctx + rowA * HID + (kg - 512);
      else                 src = h0 + rowA * HID + (kg - 1536);
      float4 f0 = *(const float4*)src;
      float4 f1 = *(const float4*)(src + 4);
      union { unsigned short us[8]; uint4 u; } p;
      p.us[0]=f2bf(f0.x); p.us[1]=f2bf(f0.y); p.us[2]=f2bf(f0.z); p.us[3]=f2bf(f0.w);
      p.us[4]=f2bf(f1.x); p.us[5]=f2bf(f1.y); p.us[6]=f2bf(f1.z); p.us[7]=f2bf(f1.w);
      *(uint4*)&lA[rowA * 40 + qA] = p.u;
    }
    {  // B stage (16-seg never crosses 1536)
      int kg = k0 + hB * 16;
      const float* src = (kg < 1536) ? (W_ih + (size_t)(n0 + rowB) * 1536 + kg)
                                     : (W_hh + (size_t)(n0 + rowB) * 1024 + (kg - 1536));
      stage16(src, &lB[rowB * 40 + hB * 16]);
    }
    __syncthreads();
    bf16x8 af[4], bv[2];
    int co = (l >> 4) * 8;
#pragma unroll
    for (int i = 0; i < 4; i++) af[i] = *(const bf16x8*)&lA[(i * 16 + (l & 15)) * 40 + co];
#pragma unroll
    for (int j = 0; j < 2; j++) bv[j] = *(const bf16x8*)&lB[(w * 32 + j * 16 + (l & 15)) * 40 + co];
#pragma unroll
    for (int i = 0; i < 4; i++)
#pragma unroll
      for (int j = 0; j < 2; j++)
        acc[i][j] = __builtin_amdgcn_mfma_f32_16x16x32_bf16(af[i], bv[j], acc[i][j], 0, 0, 0);
    __syncthreads();
  }
#pragma unroll
  for (int i = 0; i < 4; i++)
#pragma unroll
    for (int j = 0; j < 2; j++) {
      int n = n0 + w * 32 + j * 16 + (l & 15);
#pragma unroll
      for (int r = 0; r < 4; r++) {
        int m = i * 16 + (l >> 4) * 4 + r;
        gpart[(size_t)kz * 262144 + (size_t)m * 4096 + n] = acc[i][j][r];
      }
    }
}

// ------- LSTM pointwise (fused 8-plane gate combine) -> h1, c1 -------
__global__ void lstm_kernel(const float* __restrict__ gpart, const float* __restrict__ b_ih,
                            const float* __restrict__ b_hh, const float* __restrict__ c0,
                            float* __restrict__ out) {
  int b = blockIdx.y;
  int hh = blockIdx.x * 256 + threadIdx.x;
  float gi = b_ih[hh]        + b_hh[hh];
  float gf = b_ih[1024 + hh] + b_hh[1024 + hh];
  float gg = b_ih[2048 + hh] + b_hh[2048 + hh];
  float go = b_ih[3072 + hh] + b_hh[3072 + hh];
#pragma unroll
  for (int kz = 0; kz < 8; kz++) {
    const float* g = gpart + (size_t)kz * 262144 + (size_t)b * 4096;
    gi += g[hh];
    gf += g[1024 + hh];
    gg += g[2048 + hh];
    go += g[3072 + hh];
  }
  float si = 1.f / (1.f + expf(-gi));
  float sf = 1.f / (1.f + expf(-gf));
  float so = 1.f / (1.f + expf(-go));
  float c1 = sf * c0[b * HID + hh] + si * tanhf(gg);
  float h1 = so * tanhf(c1);
  out[OUT_H1 + b * HID + hh] = h1;
  out[OUT_C1 + b * HID + hh] = c1;
}

// ---- fc: K-split x2, partial planes (single-buffer) ----
__launch_bounds__(256)
__global__ void fc2p_kernel(const float* __restrict__ h1, const float* __restrict__ ctx,
                            const float* __restrict__ fcW, float* __restrict__ part) {
  __shared__ __align__(16) unsigned short lA[64 * 40];
  __shared__ __align__(16) unsigned short lB[128 * 40];
  int n0 = blockIdx.x * 128, kz = blockIdx.y;
  const float* A = kz ? ctx : h1;
  int t = threadIdx.x, w = t >> 6, l = t & 63;
  f32x4 acc[4][2];
#pragma unroll
  for (int i = 0; i < 4; i++)
#pragma unroll
    for (int j = 0; j < 2; j++) acc[i][j] = (f32x4){0.f, 0.f, 0.f, 0.f};
  int rowA = t >> 2, qA = (t & 3) * 8;
  int rowB = t >> 1, hB = t & 1;

  for (int kt = 0; kt < 32; kt++) {
    int k0 = kt * 32;
    {
      const float* src = A + rowA * HID + k0 + qA;
      float4 f0 = *(const float4*)src;
      float4 f1 = *(const float4*)(src + 4);
      union { unsigned short us[8]; uint4 u; } p;
      p.us[0]=f2bf(f0.x); p.us[1]=f2bf(f0.y); p.us[2]=f2bf(f0.z); p.us[3]=f2bf(f0.w);
      p.us[4]=f2bf(f1.x); p.us[5]=f2bf(f1.y); p.us[6]=f2bf(f1.z); p.us[7]=f2bf(f1.w);
      *(uint4*)&lA[rowA * 40 + qA] = p.u;
    }
    stage16(fcW + (size_t)(n0 + rowB) * 2048 + kz * 1024 + k0 + hB * 16,
            &lB[rowB * 40 + hB * 16]);
    __syncthreads();
    bf16x8 af[4], bv[2];
    int co = (l >> 4) * 8;
#pragma unroll
    for (int i = 0; i < 4; i++) af[i] = *(const bf16x8*)&lA[(i * 16 + (l & 15)) * 40 + co];
#pragma unroll
    for (int j = 0; j < 2; j++) bv[j] = *(const bf16x8*)&lB[(w * 32 + j * 16 + (l & 15)) * 40 + co];
#pragma unroll
    for (int i = 0; i < 4; i++)
#pragma unroll
      for (int j = 0; j < 2; j++)
        acc[i][j] = __builtin_amdgcn_mfma_f32_16x16x32_bf16(af[i], bv[j], acc[i][j], 0, 0, 0);
    __syncthreads();
  }
#pragma unroll
  for (int i = 0; i < 4; i++)
#pragma unroll
    for (int j = 0; j < 2; j++) {
      int n = n0 + w * 32 + j * 16 + (l & 15);
#pragma unroll
      for (int r = 0; r < 4; r++) {
        int m = i * 16 + (l >> 4) * 4 + r;
        part[(size_t)kz * 2048000 + (size_t)m * VOCAB + n] = acc[i][j][r];
      }
    }
}

__global__ void fc_combine_kernel(const float* __restrict__ part,
                                  const float* __restrict__ fcb, float* __restrict__ pred) {
  int i = blockIdx.x * 256 + threadIdx.x;   // 2000*256 = 512000 float4s
  int m = i / 8000, n4 = i % 8000;
  size_t e = (size_t)m * VOCAB + n4 * 4;
  float4 p0 = *(const float4*)(part + e);
  float4 p1 = *(const float4*)(part + 2048000 + e);
  float4 bb = *(const float4*)(fcb + n4 * 4);
  float4 o;
  o.x = p0.x + p1.x + bb.x;
  o.y = p0.y + p1.y + bb.y;
  o.z = p0.z + p1.z + bb.z;
  o.w = p0.w + p1.w + bb.w;
  *(float4*)(pred + e) = o;
}

extern "C" void kernel_launch(void* const* d_in, const int* in_sizes, int n_in,
                              void* d_out, int out_size, void* d_ws, size_t ws_size,
                              hipStream_t stream) {
  const int*   tok  = (const int*)d_in[0];
  const float* h    = (const float*)d_in[1];
  const float* c    = (const float*)d_in[2];
  const float* enc  = (const float*)d_in[3];
  const float* emb  = (const float*)d_in[4];
  const float* W1   = (const float*)d_in[5];
  const float* W2   = (const float*)d_in[6];
  const float* v    = (const float*)d_in[7];
  const float* W_ih = (const float*)d_in[8];
  const float* W_hh = (const float*)d_in[9];
  const float* b_ih = (const float*)d_in[10];
  const float* b_hh = (const float*)d_in[11];
  const float* fcW  = (const float*)d_in[12];
  const float* fcb  = (const float*)d_in[13];
  float* out = (float*)d_out;

  float* wsf    = (float*)d_ws;
  float* scores = wsf;             // 32768
  float* ctx    = wsf + 32768;     // 65536   (zeroed with scores: 98304 total)
  float* dh     = wsf + 98304;     // 65536
  float* gpart  = wsf + 163840;    // 8*262144 = 2097152
  float* part   = wsf + 2260992;   // 2*2048000 = 4096000
  unsigned short* encb = (unsigned short*)(wsf + 6356992);   // 33,554,432 bf16
  unsigned short* W2b  = encb + (size_t)BATCH * SEQ * HID;   //  1,048,576 bf16

  zero_ws_kernel<<<96, 256, 0, stream>>>(wsf);   // scores+ctx (atomic targets)

  f2bf_kernel<<<2048, 256, 0, stream>>>(enc, encb, BATCH * SEQ * HID / 8);
  f2bf_kernel<<<512, 256, 0, stream>>>(W2, W2b, HID * HID / 8);
  dh_kernel<<<dim3(4, 64), 256, 0, stream>>>(h, W1, dh);
  scores8_kernel<<<512, 512, 0, stream>>>(encb, W2b, dh, v, scores);
  softmax_kernel<<<64, 512, 0, stream>>>(scores, out + OUT_ATTN);
  context2_kernel<<<dim3(8, 64), 256, 0, stream>>>(encb, out + OUT_ATTN, ctx);
  gates8p_kernel<<<dim3(32, 8), 256, 0, stream>>>(tok, emb, ctx, h, W_ih, W_hh, gpart);
  lstm_kernel<<<dim3(4, 64), 256, 0, stream>>>(gpart, b_ih, b_hh, c, out);
  fc2p_kernel<<<dim3(250, 2), 256, 0, stream>>>(out + OUT_H1, ctx, fcW, part);
  fc_combine_kernel<<<2000, 256, 0, stream>>>(part, fcb, out);
}

// Round 11
// 292.864 us; speedup vs baseline: 1.1830x; 1.0187x over previous
//
#include <hip/hip_runtime.h>
#include <math.h>

#define VOCAB 32000
#define EMBED 512
#define HID   1024
#define BATCH 64
#define SEQ   512

// d_out layout (floats): pred[64*32000]=0 .. 2048000 ; h1 @2048000 ; c1 @2113536 ; attn @2179072
#define OUT_H1   2048000
#define OUT_C1   2113536
#define OUT_ATTN 2179072

typedef __bf16 bf16x8 __attribute__((ext_vector_type(8)));
typedef float  f32x4  __attribute__((ext_vector_type(4)));

__device__ __forceinline__ unsigned short f2bf(float f) {
  unsigned int u = __builtin_bit_cast(unsigned int, f);
  u += 0x7fffu + ((u >> 16) & 1u);   // round-to-nearest-even
  return (unsigned short)(u >> 16);
}
__device__ __forceinline__ float bf2f(unsigned int u) {
  return __builtin_bit_cast(float, u << 16);
}

// fast tanh: (e^{2x}-1)/(e^{2x}+1) via hw exp2; clamp avoids inf/inf
__device__ __forceinline__ float fast_tanh(float x) {
  float cx = fminf(fmaxf(x, -15.f), 15.f);
  float t = __builtin_amdgcn_exp2f(cx * 2.8853900817779268f);  // e^{2x}
  return (t - 1.f) / (t + 1.f);
}

// async 16B/lane global->LDS; lds ptr must be wave-uniform (HW: base + lane*16)
__device__ __forceinline__ void gload16(const unsigned short* g, unsigned short* l) {
  __builtin_amdgcn_global_load_lds(
      (const __attribute__((address_space(1))) void*)g,
      (__attribute__((address_space(3))) void*)l, 16, 0, 0);
}

// 16 f32 -> 16 bf16 (RNE bit-trick), 32B to LDS
__device__ __forceinline__ void stage16(const float* __restrict__ src, unsigned short* dst) {
  float4 f0 = *(const float4*)(src + 0);
  float4 f1 = *(const float4*)(src + 4);
  float4 f2 = *(const float4*)(src + 8);
  float4 f3 = *(const float4*)(src + 12);
  union { unsigned short us[16]; uint4 u4[2]; } p;
  p.us[0]=f2bf(f0.x);  p.us[1]=f2bf(f0.y);  p.us[2]=f2bf(f0.z);  p.us[3]=f2bf(f0.w);
  p.us[4]=f2bf(f1.x);  p.us[5]=f2bf(f1.y);  p.us[6]=f2bf(f1.z);  p.us[7]=f2bf(f1.w);
  p.us[8]=f2bf(f2.x);  p.us[9]=f2bf(f2.y);  p.us[10]=f2bf(f2.z); p.us[11]=f2bf(f2.w);
  p.us[12]=f2bf(f3.x); p.us[13]=f2bf(f3.y); p.us[14]=f2bf(f3.z); p.us[15]=f2bf(f3.w);
  *(uint4*)(dst + 0) = p.u4[0];
  *(uint4*)(dst + 8) = p.u4[1];
}

// ---- zero scores+ctx (atomic targets): 98304 floats ----
__global__ void zero_ws_kernel(float* __restrict__ p) {
  int i = blockIdx.x * 256 + threadIdx.x;     // 96*256 threads * 4 floats = 98304
  *(float4*)(p + (size_t)i * 4) = (float4){0.f, 0.f, 0.f, 0.f};
}

// ------------- f32 -> bf16 bulk convert (grid-stride, 8 elems/thread/iter) -------------
__global__ void f2bf_kernel(const float* __restrict__ src, unsigned short* __restrict__ dst,
                            int n8) {
  int i = blockIdx.x * blockDim.x + threadIdx.x;
  int stride = gridDim.x * blockDim.x;
  for (; i < n8; i += stride) {
    const float* s = src + (size_t)i * 8;
    float4 f0 = *(const float4*)s;
    float4 f1 = *(const float4*)(s + 4);
    union { unsigned short us[8]; uint4 u; } p;
    p.us[0]=f2bf(f0.x); p.us[1]=f2bf(f0.y); p.us[2]=f2bf(f0.z); p.us[3]=f2bf(f0.w);
    p.us[4]=f2bf(f1.x); p.us[5]=f2bf(f1.y); p.us[6]=f2bf(f1.z); p.us[7]=f2bf(f1.w);
    *(uint4*)(dst + (size_t)i * 8) = p.u;
  }
}

// ---- dh = h0 @ W1^T (blocks 0..255) + W2 f32->bf16 (blocks 256..767) ----
__global__ void dh_w2_kernel(const float* __restrict__ h0, const float* __restrict__ W1,
                             float* __restrict__ dh,
                             const float* __restrict__ W2, unsigned short* __restrict__ W2b) {
  __shared__ float hs[HID];
  int bid = blockIdx.x, t = threadIdx.x;
  if (bid < 256) {
    int b = bid >> 2, kblk = bid & 3;
    for (int i = t; i < HID; i += 256) hs[i] = h0[b * HID + i];
    __syncthreads();
    int k = kblk * 256 + t;
    const float* w = W1 + (size_t)k * HID;
    float acc = 0.f;
    for (int hh = 0; hh < HID; hh += 4) {
      float4 wv = *(const float4*)(w + hh);
      float4 hv = *(const float4*)(hs + hh);
      acc += wv.x * hv.x + wv.y * hv.y + wv.z * hv.z + wv.w * hv.w;
    }
    dh[b * HID + k] = acc;
  } else {
    int i = (bid - 256) * 256 + t;   // 512*256 = 131072 groups of 8 = HID*HID/8
    const float* s = W2 + (size_t)i * 8;
    float4 f0 = *(const float4*)s;
    float4 f1 = *(const float4*)(s + 4);
    union { unsigned short us[8]; uint4 u; } p;
    p.us[0]=f2bf(f0.x); p.us[1]=f2bf(f0.y); p.us[2]=f2bf(f0.z); p.us[3]=f2bf(f0.w);
    p.us[4]=f2bf(f1.x); p.us[5]=f2bf(f1.y); p.us[6]=f2bf(f1.z); p.us[7]=f2bf(f1.w);
    *(uint4*)(W2b + (size_t)i * 8) = p.u;
  }
}

// ==== scores: 256x256 tile, BK=64, 8 waves, counted-vmcnt pipeline ====
// LDS swizzle upgraded: elem ^= (row&7)<<3 — spreads each b128 read uniformly
// over all 8 bank-quads (8 lanes/quad = optimal), vs 4 quads (16/quad) before.
// Applied via pre-swizzled GLOBAL source (gload_lds writes linearly) + same
// XOR on ds_read. Involution verified: read(elem)^swz then ^swz = identity.
__launch_bounds__(512, 2)
__global__ void scores8_kernel(const unsigned short* __restrict__ encb,
                               const unsigned short* __restrict__ W2b,
                               const float* __restrict__ dh, const float* __restrict__ v,
                               float* __restrict__ scores) {
  __shared__ __align__(16) unsigned short sA[2][16384];  // [dbuf][256 rows * 64 k]
  __shared__ __align__(16) unsigned short sB[2][16384];
  __shared__ float dh_s[256];
  __shared__ float v_s[256];

  int bid = blockIdx.x;
  int wg = (bid & 7) * 64 + (bid >> 3);
  int mt = wg >> 2, nt = wg & 3;
  int m0 = mt * 256, n0 = nt * 256;

  int t = threadIdx.x;
  int wid = t >> 6, l = t & 63;
  int wr = wid >> 2, wc = wid & 3;     // 2 M-waves x 4 N-waves
  int fr = l & 15, co = (l >> 4) * 8;

  // Stage-source for the (row&7)<<3 elem-swizzle:
  // lane l of wave wid covers LDS row (wid*8 + (l>>3)), elems [(l&7)*8, +8);
  // global col = ((l&7) ^ ((l>>3)&7)) * 8. Chunk c adds c*64 rows (uniform).
  const unsigned short* pa0;
  const unsigned short* pb0;
  int do0 = wid * 512;  // LDS elem offset of this wave's 1KB slice in chunk 0
  {
    int row0 = wid * 8 + (l >> 3);
    int colE = ((l & 7) ^ ((l >> 3) & 7)) << 3;
    pa0 = encb + (size_t)(m0 + row0) * HID + colE;
    pb0 = W2b + (size_t)(n0 + row0) * HID + colE;
  }

  f32x4 acc[8][4];
#pragma unroll
  for (int i = 0; i < 8; i++)
#pragma unroll
    for (int j = 0; j < 4; j++) acc[i][j] = (f32x4){0.f, 0.f, 0.f, 0.f};

#define SC_STAGE(T, d)                                                         \
  do {                                                                         \
    int k0_ = (T) * 64;                                                        \
    gload16(pa0 + k0_,          &sA[d][do0]);                                  \
    gload16(pa0 + 65536 + k0_,  &sA[d][do0 + 4096]);                           \
    gload16(pa0 + 131072 + k0_, &sA[d][do0 + 8192]);                           \
    gload16(pa0 + 196608 + k0_, &sA[d][do0 + 12288]);                          \
    gload16(pb0 + k0_,          &sB[d][do0]);                                  \
    gload16(pb0 + 65536 + k0_,  &sB[d][do0 + 4096]);                           \
    gload16(pb0 + 131072 + k0_, &sB[d][do0 + 8192]);                           \
    gload16(pb0 + 196608 + k0_, &sB[d][do0 + 12288]);                          \
  } while (0)

  SC_STAGE(0, 0);
  SC_STAGE(1, 1);

  // swizzled ds_read: elem col ^= (row&7)<<3
#define LDF(Mat, row, ks) \
  (*(const bf16x8*)&Mat[(row) * 64 + (((ks) * 32 + co) ^ (((row) & 7) << 3))])

  for (int T = 0; T < 16; ++T) {
    int d = T & 1;
    if (T == 15) asm volatile("s_waitcnt vmcnt(0)" ::: "memory");
    else         asm volatile("s_waitcnt vmcnt(8)" ::: "memory");
    asm volatile("s_barrier" ::: "memory");
    const unsigned short* A = sA[d];
    const unsigned short* B = sB[d];
    bf16x8 a[4][2], b[4][2];
#pragma unroll
    for (int jj = 0; jj < 4; ++jj)
#pragma unroll
      for (int ks = 0; ks < 2; ++ks)
        b[jj][ks] = LDF(B, wc * 64 + jj * 16 + fr, ks);
#pragma unroll
    for (int ii = 0; ii < 4; ++ii)
#pragma unroll
      for (int ks = 0; ks < 2; ++ks)
        a[ii][ks] = LDF(A, wr * 128 + ii * 16 + fr, ks);
    __builtin_amdgcn_s_setprio(1);
#pragma unroll
    for (int ii = 0; ii < 4; ++ii)
#pragma unroll
      for (int jj = 0; jj < 2; ++jj)
#pragma unroll
        for (int ks = 0; ks < 2; ++ks)
          acc[ii][jj] = __builtin_amdgcn_mfma_f32_16x16x32_bf16(a[ii][ks], b[jj][ks], acc[ii][jj], 0, 0, 0);
    __builtin_amdgcn_s_setprio(0);
    __builtin_amdgcn_s_setprio(1);
#pragma unroll
    for (int ii = 0; ii < 4; ++ii)
#pragma unroll
      for (int jj = 2; jj < 4; ++jj)
#pragma unroll
        for (int ks = 0; ks < 2; ++ks)
          acc[ii][jj] = __builtin_amdgcn_mfma_f32_16x16x32_bf16(a[ii][ks], b[jj][ks], acc[ii][jj], 0, 0, 0);
    __builtin_amdgcn_s_setprio(0);
#pragma unroll
    for (int ii = 0; ii < 4; ++ii)
#pragma unroll
      for (int ks = 0; ks < 2; ++ks)
        a[ii][ks] = LDF(A, wr * 128 + 64 + ii * 16 + fr, ks);
    __builtin_amdgcn_s_setprio(1);
#pragma unroll
    for (int ii = 0; ii < 4; ++ii)
#pragma unroll
      for (int jj = 2; jj < 4; ++jj)
#pragma unroll
        for (int ks = 0; ks < 2; ++ks)
          acc[4 + ii][jj] = __builtin_amdgcn_mfma_f32_16x16x32_bf16(a[ii][ks], b[jj][ks], acc[4 + ii][jj], 0, 0, 0);
    __builtin_amdgcn_s_setprio(0);
    __builtin_amdgcn_s_setprio(1);
#pragma unroll
    for (int ii = 0; ii < 4; ++ii)
#pragma unroll
      for (int jj = 0; jj < 2; ++jj)
#pragma unroll
        for (int ks = 0; ks < 2; ++ks)
          acc[4 + ii][jj] = __builtin_amdgcn_mfma_f32_16x16x32_bf16(a[ii][ks], b[jj][ks], acc[4 + ii][jj], 0, 0, 0);
    __builtin_amdgcn_s_setprio(0);
    asm volatile("s_barrier" ::: "memory");   // all reads of dbuf d done
    if (T < 14) SC_STAGE(T + 2, d);           // prefetch tile T+2 into dbuf d
  }
#undef LDF
#undef SC_STAGE

  // epilogue: partial scores over this 256-wide n-tile (fast_tanh)
  int b = m0 >> 9;
  if (t < 256) { dh_s[t] = dh[b * HID + n0 + t]; v_s[t] = v[n0 + t]; }
  __syncthreads();
  float sp[32];
#pragma unroll
  for (int q = 0; q < 32; ++q) sp[q] = 0.f;
#pragma unroll
  for (int ii = 0; ii < 8; ++ii)
#pragma unroll
    for (int jj = 0; jj < 4; ++jj) {
      int nl = wc * 64 + jj * 16 + fr;
      float dv = dh_s[nl], vv = v_s[nl];
#pragma unroll
      for (int r = 0; r < 4; ++r)
        sp[ii * 4 + r] += fast_tanh(dv + acc[ii][jj][r]) * vv;
    }
#pragma unroll
  for (int q = 0; q < 32; ++q) {
    float x = sp[q];
    x += __shfl_xor(x, 1);
    x += __shfl_xor(x, 2);
    x += __shfl_xor(x, 4);
    x += __shfl_xor(x, 8);
    sp[q] = x;
  }
  if (fr == 0) {
    int rbase = m0 + wr * 128 + (l >> 4) * 4;
#pragma unroll
    for (int ii = 0; ii < 8; ++ii)
#pragma unroll
      for (int r = 0; r < 4; ++r)
        atomicAdd(&scores[rbase + ii * 16 + r], sp[ii * 4 + r]);
  }
}

// ---------------- softmax over S per batch row ----------------
__global__ void softmax_kernel(const float* __restrict__ scores, float* __restrict__ attn) {
  __shared__ float red[8];
  int b = blockIdx.x, t = threadIdx.x;  // 512 threads
  float x = scores[b * SEQ + t];
  float m = x;
  for (int d = 1; d < 64; d <<= 1) m = fmaxf(m, __shfl_xor(m, d));
  if ((t & 63) == 0) red[t >> 6] = m;
  __syncthreads();
  float bm = red[0];
#pragma unroll
  for (int i = 1; i < 8; i++) bm = fmaxf(bm, red[i]);
  float e = expf(x - bm);
  float s = e;
  for (int d = 1; d < 64; d <<= 1) s += __shfl_xor(s, d);
  __syncthreads();
  if ((t & 63) == 0) red[t >> 6] = s;
  __syncthreads();
  float bs = 0.f;
#pragma unroll
  for (int i = 0; i < 8; i++) bs += red[i];
  attn[b * SEQ + t] = e / bs;
}

// ------- context: bf16 enc, 16B/lane; ctx[b,h] = sum_s attn[b,s]*enc[b,s,h] -------
__global__ void context2_kernel(const unsigned short* __restrict__ encb,
                                const float* __restrict__ attn, float* __restrict__ ctx) {
  __shared__ float a_s[64];
  int b = blockIdx.y, s0 = blockIdx.x * 64, t = threadIdx.x;
  if (t < 64) a_s[t] = attn[b * SEQ + s0 + t];
  __syncthreads();
  int hg = (t & 127) * 8, sg = (t >> 7) * 32;  // 128 h-threads x 2 s-groups
  float a0 = 0.f, a1 = 0.f, a2 = 0.f, a3 = 0.f, a4 = 0.f, a5 = 0.f, a6 = 0.f, a7 = 0.f;
  const unsigned short* base = encb + ((size_t)b * SEQ + s0 + sg) * HID + hg;
  for (int s = 0; s < 32; s++) {
    uint4 ev = *(const uint4*)(base + (size_t)s * HID);
    float a = a_s[sg + s];
    a0 += a * bf2f(ev.x & 0xffffu); a1 += a * bf2f(ev.x >> 16);
    a2 += a * bf2f(ev.y & 0xffffu); a3 += a * bf2f(ev.y >> 16);
    a4 += a * bf2f(ev.z & 0xffffu); a5 += a * bf2f(ev.z >> 16);
    a6 += a * bf2f(ev.w & 0xffffu); a7 += a * bf2f(ev.w >> 16);
  }
  atomicAdd(&ctx[b * HID + hg + 0], a0);
  atomicAdd(&ctx[b * HID + hg + 1], a1);
  atomicAdd(&ctx[b * HID + hg + 2], a2);
  atomicAdd(&ctx[b * HID + hg + 3], a3);
  atomicAdd(&ctx[b * HID + hg + 4], a4);
  atomicAdd(&ctx[b * HID + hg + 5], a5);
  atomicAdd(&ctx[b * HID + hg + 6], a6);
  atomicAdd(&ctx[b * HID + hg + 7], a7);
}

// ==== gates via MFMA: gpart[kz] = x @ W[:, kz*320:+320]^T  (M=64, N=4096) ====
__launch_bounds__(256)
__global__ void gates8p_kernel(const int* __restrict__ tok, const float* __restrict__ emb,
                               const float* __restrict__ ctx, const float* __restrict__ h0,
                               const float* __restrict__ W_ih, const float* __restrict__ W_hh,
                               float* __restrict__ gpart) {
  __shared__ __align__(16) unsigned short lA[64 * 40];
  __shared__ __align__(16) unsigned short lB[128 * 40];
  int n0 = blockIdx.x * 128, kz = blockIdx.y;   // 32 n-blocks x 8 K-slices
  int kbase = kz * 320;
  int t = threadIdx.x, w = t >> 6, l = t & 63;
  f32x4 acc[4][2];
#pragma unroll
  for (int i = 0; i < 4; i++)
#pragma unroll
    for (int j = 0; j < 2; j++) acc[i][j] = (f32x4){0.f, 0.f, 0.f, 0.f};
  int rowA = t >> 2, qA = (t & 3) * 8;   // 64 rows x 4 quads of 8
  int rowB = t >> 1, hB = t & 1;         // 128 rows x 2 halves of 16
  int tkA = tok[rowA];

  for (int kt = 0; kt < 10; kt++) {
    int k0 = kbase + kt * 32;
    {  // A stage (segments never cross 512/1536)
      int kg = k0 + qA;
      const float* src;
      if (kg < 512)        src = emb + (size_t)tkA * EMBED + kg;
      else if (kg < 1536)  src = ctx + rowA * HID + (kg - 512);
      else                 src = h0 + rowA * HID + (kg - 1536);
      float4 f0 = *(const float4*)src;
      float4 f1 = *(const float4*)(src + 4);
      union { unsigned short us[8]; uint4 u; } p;
      p.us[0]=f2bf(f0.x); p.us[1]=f2bf(f0.y); p.us[2]=f2bf(f0.z); p.us[3]=f2bf(f0.w);
      p.us[4]=f2bf(f1.x); p.us[5]=f2bf(f1.y); p.us[6]=f2bf(f1.z); p.us[7]=f2bf(f1.w);
      *(uint4*)&lA[rowA * 40 + qA] = p.u;
    }
    {  // B stage (16-seg never crosses 1536)
      int kg = k0 + hB * 16;
      const float* src = (kg < 1536) ? (W_ih + (size_t)(n0 + rowB) * 1536 + kg)
                                     : (W_hh + (size_t)(n0 + rowB) * 1024 + (kg - 1536));
      stage16(src, &lB[rowB * 40 + hB * 16]);
    }
    __syncthreads();
    bf16x8 af[4], bv[2];
    int co = (l >> 4) * 8;
#pragma unroll
    for (int i = 0; i < 4; i++) af[i] = *(const bf16x8*)&lA[(i * 16 + (l & 15)) * 40 + co];
#pragma unroll
    for (int j = 0; j < 2; j++) bv[j] = *(const bf16x8*)&lB[(w * 32 + j * 16 + (l & 15)) * 40 + co];
#pragma unroll
    for (int i = 0; i < 4; i++)
#pragma unroll
      for (int j = 0; j < 2; j++)
        acc[i][j] = __builtin_amdgcn_mfma_f32_16x16x32_bf16(af[i], bv[j], acc[i][j], 0, 0, 0);
    __syncthreads();
  }
#pragma unroll
  for (int i = 0; i < 4; i++)
#pragma unroll
    for (int j = 0; j < 2; j++) {
      int n = n0 + w * 32 + j * 16 + (l & 15);
#pragma unroll
      for (int r = 0; r < 4; r++) {
        int m = i * 16 + (l >> 4) * 4 + r;
        gpart[(size_t)kz * 262144 + (size_t)m * 4096 + n] = acc[i][j][r];
      }
    }
}

// ------- LSTM pointwise (fused 8-plane gate combine) -> h1, c1 -------
__global__ void lstm_kernel(const float* __restrict__ gpart, const float* __restrict__ b_ih,
                            const float* __restrict__ b_hh, const float* __restrict__ c0,
                            float* __restrict__ out) {
  int b = blockIdx.y;
  int hh = blockIdx.x * 256 + threadIdx.x;
  float gi = b_ih[hh]        + b_hh[hh];
  float gf = b_ih[1024 + hh] + b_hh[1024 + hh];
  float gg = b_ih[2048 + hh] + b_hh[2048 + hh];
  float go = b_ih[3072 + hh] + b_hh[3072 + hh];
#pragma unroll
  for (int kz = 0; kz < 8; kz++) {
    const float* g = gpart + (size_t)kz * 262144 + (size_t)b * 4096;
    gi += g[hh];
    gf += g[1024 + hh];
    gg += g[2048 + hh];
    go += g[3072 + hh];
  }
  float si = 1.f / (1.f + expf(-gi));
  float sf = 1.f / (1.f + expf(-gf));
  float so = 1.f / (1.f + expf(-go));
  float c1 = sf * c0[b * HID + hh] + si * tanhf(gg);
  float h1 = so * tanhf(c1);
  out[OUT_H1 + b * HID + hh] = h1;
  out[OUT_C1 + b * HID + hh] = c1;
}

// ---- fc: K-split x2, partial planes (single-buffer, r7-proven) ----
__launch_bounds__(256)
__global__ void fc2p_kernel(const float* __restrict__ h1, const float* __restrict__ ctx,
                            const float* __restrict__ fcW, float* __restrict__ part) {
  __shared__ __align__(16) unsigned short lA[64 * 40];
  __shared__ __align__(16) unsigned short lB[128 * 40];
  int n0 = blockIdx.x * 128, kz = blockIdx.y;
  const float* A = kz ? ctx : h1;
  int t = threadIdx.x, w = t >> 6, l = t & 63;
  f32x4 acc[4][2];
#pragma unroll
  for (int i = 0; i < 4; i++)
#pragma unroll
    for (int j = 0; j < 2; j++) acc[i][j] = (f32x4){0.f, 0.f, 0.f, 0.f};
  int rowA = t >> 2, qA = (t & 3) * 8;
  int rowB = t >> 1, hB = t & 1;

  for (int kt = 0; kt < 32; kt++) {
    int k0 = kt * 32;
    {
      const float* src = A + rowA * HID + k0 + qA;
      float4 f0 = *(const float4*)src;
      float4 f1 = *(const float4*)(src + 4);
      union { unsigned short us[8]; uint4 u; } p;
      p.us[0]=f2bf(f0.x); p.us[1]=f2bf(f0.y); p.us[2]=f2bf(f0.z); p.us[3]=f2bf(f0.w);
      p.us[4]=f2bf(f1.x); p.us[5]=f2bf(f1.y); p.us[6]=f2bf(f1.z); p.us[7]=f2bf(f1.w);
      *(uint4*)&lA[rowA * 40 + qA] = p.u;
    }
    stage16(fcW + (size_t)(n0 + rowB) * 2048 + kz * 1024 + k0 + hB * 16,
            &lB[rowB * 40 + hB * 16]);
    __syncthreads();
    bf16x8 af[4], bv[2];
    int co = (l >> 4) * 8;
#pragma unroll
    for (int i = 0; i < 4; i++) af[i] = *(const bf16x8*)&lA[(i * 16 + (l & 15)) * 40 + co];
#pragma unroll
    for (int j = 0; j < 2; j++) bv[j] = *(const bf16x8*)&lB[(w * 32 + j * 16 + (l & 15)) * 40 + co];
#pragma unroll
    for (int i = 0; i < 4; i++)
#pragma unroll
      for (int j = 0; j < 2; j++)
        acc[i][j] = __builtin_amdgcn_mfma_f32_16x16x32_bf16(af[i], bv[j], acc[i][j], 0, 0, 0);
    __syncthreads();
  }
#pragma unroll
  for (int i = 0; i < 4; i++)
#pragma unroll
    for (int j = 0; j < 2; j++) {
      int n = n0 + w * 32 + j * 16 + (l & 15);
#pragma unroll
      for (int r = 0; r < 4; r++) {
        int m = i * 16 + (l >> 4) * 4 + r;
        part[(size_t)kz * 2048000 + (size_t)m * VOCAB + n] = acc[i][j][r];
      }
    }
}

__global__ void fc_combine_kernel(const float* __restrict__ part,
                                  const float* __restrict__ fcb, float* __restrict__ pred) {
  int i = blockIdx.x * 256 + threadIdx.x;   // 2000*256 = 512000 float4s
  int m = i / 8000, n4 = i % 8000;
  size_t e = (size_t)m * VOCAB + n4 * 4;
  float4 p0 = *(const float4*)(part + e);
  float4 p1 = *(const float4*)(part + 2048000 + e);
  float4 bb = *(const float4*)(fcb + n4 * 4);
  float4 o;
  o.x = p0.x + p1.x + bb.x;
  o.y = p0.y + p1.y + bb.y;
  o.z = p0.z + p1.z + bb.z;
  o.w = p0.w + p1.w + bb.w;
  *(float4*)(pred + e) = o;
}

extern "C" void kernel_launch(void* const* d_in, const int* in_sizes, int n_in,
                              void* d_out, int out_size, void* d_ws, size_t ws_size,
                              hipStream_t stream) {
  const int*   tok  = (const int*)d_in[0];
  const float* h    = (const float*)d_in[1];
  const float* c    = (const float*)d_in[2];
  const float* enc  = (const float*)d_in[3];
  const float* emb  = (const float*)d_in[4];
  const float* W1   = (const float*)d_in[5];
  const float* W2   = (const float*)d_in[6];
  const float* v    = (const float*)d_in[7];
  const float* W_ih = (const float*)d_in[8];
  const float* W_hh = (const float*)d_in[9];
  const float* b_ih = (const float*)d_in[10];
  const float* b_hh = (const float*)d_in[11];
  const float* fcW  = (const float*)d_in[12];
  const float* fcb  = (const float*)d_in[13];
  float* out = (float*)d_out;

  float* wsf    = (float*)d_ws;
  float* scores = wsf;             // 32768
  float* ctx    = wsf + 32768;     // 65536   (zeroed with scores: 98304 total)
  float* dh     = wsf + 98304;     // 65536
  float* gpart  = wsf + 163840;    // 8*262144 = 2097152
  float* part   = wsf + 2260992;   // 2*2048000 = 4096000
  unsigned short* encb = (unsigned short*)(wsf + 6356992);   // 33,554,432 bf16
  unsigned short* W2b  = encb + (size_t)BATCH * SEQ * HID;   //  1,048,576 bf16

  zero_ws_kernel<<<96, 256, 0, stream>>>(wsf);   // scores+ctx (atomic targets)
  f2bf_kernel<<<2048, 256, 0, stream>>>(enc, encb, BATCH * SEQ * HID / 8);
  dh_w2_kernel<<<768, 256, 0, stream>>>(h, W1, dh, W2, W2b);
  scores8_kernel<<<512, 512, 0, stream>>>(encb, W2b, dh, v, scores);
  softmax_kernel<<<64, 512, 0, stream>>>(scores, out + OUT_ATTN);
  context2_kernel<<<dim3(8, 64), 256, 0, stream>>>(encb, out + OUT_ATTN, ctx);
  gates8p_kernel<<<dim3(32, 8), 256, 0, stream>>>(tok, emb, ctx, h, W_ih, W_hh, gpart);
  lstm_kernel<<<dim3(4, 64), 256, 0, stream>>>(gpart, b_ih, b_hh, c, out);
  fc2p_kernel<<<dim3(250, 2), 256, 0, stream>>>(out + OUT_H1, ctx, fcW, part);
  fc_combine_kernel<<<2000, 256, 0, stream>>>(part, fcb, out);
}

// Round 12
// 271.224 us; speedup vs baseline: 1.2774x; 1.0798x over previous
//
#include <hip/hip_runtime.h>
#include <math.h>

#define VOCAB 32000
#define EMBED 512
#define HID   1024
#define BATCH 64
#define SEQ   512

// d_out layout (floats): pred[64*32000]=0 .. 2048000 ; h1 @2048000 ; c1 @2113536 ; attn @2179072
#define OUT_H1   2048000
#define OUT_C1   2113536
#define OUT_ATTN 2179072

typedef __bf16 bf16x8 __attribute__((ext_vector_type(8)));
typedef float  f32x4  __attribute__((ext_vector_type(4)));

__device__ __forceinline__ unsigned short f2bf(float f) {
  unsigned int u = __builtin_bit_cast(unsigned int, f);
  u += 0x7fffu + ((u >> 16) & 1u);   // round-to-nearest-even
  return (unsigned short)(u >> 16);
}
__device__ __forceinline__ float bf2f(unsigned int u) {
  return __builtin_bit_cast(float, u << 16);
}

// fast tanh: (e^{2x}-1)/(e^{2x}+1) via hw exp2; clamp avoids inf/inf
__device__ __forceinline__ float fast_tanh(float x) {
  float cx = fminf(fmaxf(x, -15.f), 15.f);
  float t = __builtin_amdgcn_exp2f(cx * 2.8853900817779268f);  // e^{2x}
  return (t - 1.f) / (t + 1.f);
}

// async 16B/lane global->LDS; lds ptr must be wave-uniform (HW: base + lane*16)
__device__ __forceinline__ void gload16(const unsigned short* g, unsigned short* l) {
  __builtin_amdgcn_global_load_lds(
      (const __attribute__((address_space(1))) void*)g,
      (__attribute__((address_space(3))) void*)l, 16, 0, 0);
}

// ------------- f32 -> bf16 bulk convert (grid-stride, 8 elems/thread/iter) -------------
__global__ void f2bf_kernel(const float* __restrict__ src, unsigned short* __restrict__ dst,
                            int n8) {
  int i = blockIdx.x * blockDim.x + threadIdx.x;
  int stride = gridDim.x * blockDim.x;
  for (; i < n8; i += stride) {
    const float* s = src + (size_t)i * 8;
    float4 f0 = *(const float4*)s;
    float4 f1 = *(const float4*)(s + 4);
    union { unsigned short us[8]; uint4 u; } p;
    p.us[0]=f2bf(f0.x); p.us[1]=f2bf(f0.y); p.us[2]=f2bf(f0.z); p.us[3]=f2bf(f0.w);
    p.us[4]=f2bf(f1.x); p.us[5]=f2bf(f1.y); p.us[6]=f2bf(f1.z); p.us[7]=f2bf(f1.w);
    *(uint4*)(dst + (size_t)i * 8) = p.u;
  }
}

// ---- dh = h0 @ W1^T (blocks 0..255) + W2 f32->bf16 (blocks 256..767) ----
__global__ void dh_w2_kernel(const float* __restrict__ h0, const float* __restrict__ W1,
                             float* __restrict__ dh,
                             const float* __restrict__ W2, unsigned short* __restrict__ W2b) {
  __shared__ float hs[HID];
  int bid = blockIdx.x, t = threadIdx.x;
  if (bid < 256) {
    int b = bid >> 2, kblk = bid & 3;
    for (int i = t; i < HID; i += 256) hs[i] = h0[b * HID + i];
    __syncthreads();
    int k = kblk * 256 + t;
    const float* w = W1 + (size_t)k * HID;
    float acc = 0.f;
    for (int hh = 0; hh < HID; hh += 4) {
      float4 wv = *(const float4*)(w + hh);
      float4 hv = *(const float4*)(hs + hh);
      acc += wv.x * hv.x + wv.y * hv.y + wv.z * hv.z + wv.w * hv.w;
    }
    dh[b * HID + k] = acc;
  } else {
    int i = (bid - 256) * 256 + t;   // 512*256 = 131072 groups of 8 = HID*HID/8
    const float* s = W2 + (size_t)i * 8;
    float4 f0 = *(const float4*)s;
    float4 f1 = *(const float4*)(s + 4);
    union { unsigned short us[8]; uint4 u; } p;
    p.us[0]=f2bf(f0.x); p.us[1]=f2bf(f0.y); p.us[2]=f2bf(f0.z); p.us[3]=f2bf(f0.w);
    p.us[4]=f2bf(f1.x); p.us[5]=f2bf(f1.y); p.us[6]=f2bf(f1.z); p.us[7]=f2bf(f1.w);
    *(uint4*)(W2b + (size_t)i * 8) = p.u;
  }
}

// ==== scores: 256x256 tile, BK=64, 8 waves, counted-vmcnt pipeline ====
// Epilogue: in-block wc-reduction via LDS, plain store into 4 nt partial
// planes (no atomics, no pre-zero). spart[nt*32768 + global_row].
__launch_bounds__(512, 2)
__global__ void scores8_kernel(const unsigned short* __restrict__ encb,
                               const unsigned short* __restrict__ W2b,
                               const float* __restrict__ dh, const float* __restrict__ v,
                               float* __restrict__ spart) {
  __shared__ __align__(16) unsigned short sA[2][16384];  // [dbuf][256 rows * 64 k]
  __shared__ __align__(16) unsigned short sB[2][16384];
  __shared__ float dh_s[256];
  __shared__ float v_s[256];
  __shared__ float red4[4][256];

  int bid = blockIdx.x;
  int wg = (bid & 7) * 64 + (bid >> 3);
  int mt = wg >> 2, nt = wg & 3;
  int m0 = mt * 256, n0 = nt * 256;

  int t = threadIdx.x;
  int wid = t >> 6, l = t & 63;
  int wr = wid >> 2, wc = wid & 3;     // 2 M-waves x 4 N-waves
  int fr = l & 15, co = (l >> 4) * 8;

  // Stage-source for the (row&7)<<3 elem-swizzle (r11-verified)
  const unsigned short* pa0;
  const unsigned short* pb0;
  int do0 = wid * 512;
  {
    int row0 = wid * 8 + (l >> 3);
    int colE = ((l & 7) ^ ((l >> 3) & 7)) << 3;
    pa0 = encb + (size_t)(m0 + row0) * HID + colE;
    pb0 = W2b + (size_t)(n0 + row0) * HID + colE;
  }

  f32x4 acc[8][4];
#pragma unroll
  for (int i = 0; i < 8; i++)
#pragma unroll
    for (int j = 0; j < 4; j++) acc[i][j] = (f32x4){0.f, 0.f, 0.f, 0.f};

#define SC_STAGE(T, d)                                                         \
  do {                                                                         \
    int k0_ = (T) * 64;                                                        \
    gload16(pa0 + k0_,          &sA[d][do0]);                                  \
    gload16(pa0 + 65536 + k0_,  &sA[d][do0 + 4096]);                           \
    gload16(pa0 + 131072 + k0_, &sA[d][do0 + 8192]);                           \
    gload16(pa0 + 196608 + k0_, &sA[d][do0 + 12288]);                          \
    gload16(pb0 + k0_,          &sB[d][do0]);                                  \
    gload16(pb0 + 65536 + k0_,  &sB[d][do0 + 4096]);                           \
    gload16(pb0 + 131072 + k0_, &sB[d][do0 + 8192]);                           \
    gload16(pb0 + 196608 + k0_, &sB[d][do0 + 12288]);                          \
  } while (0)

  SC_STAGE(0, 0);
  SC_STAGE(1, 1);

  // swizzled ds_read: elem col ^= (row&7)<<3
#define LDF(Mat, row, ks) \
  (*(const bf16x8*)&Mat[(row) * 64 + (((ks) * 32 + co) ^ (((row) & 7) << 3))])

  for (int T = 0; T < 16; ++T) {
    int d = T & 1;
    if (T == 15) asm volatile("s_waitcnt vmcnt(0)" ::: "memory");
    else         asm volatile("s_waitcnt vmcnt(8)" ::: "memory");
    asm volatile("s_barrier" ::: "memory");
    const unsigned short* A = sA[d];
    const unsigned short* B = sB[d];
    bf16x8 a[4][2], b[4][2];
#pragma unroll
    for (int jj = 0; jj < 4; ++jj)
#pragma unroll
      for (int ks = 0; ks < 2; ++ks)
        b[jj][ks] = LDF(B, wc * 64 + jj * 16 + fr, ks);
#pragma unroll
    for (int ii = 0; ii < 4; ++ii)
#pragma unroll
      for (int ks = 0; ks < 2; ++ks)
        a[ii][ks] = LDF(A, wr * 128 + ii * 16 + fr, ks);
    __builtin_amdgcn_s_setprio(1);
#pragma unroll
    for (int ii = 0; ii < 4; ++ii)
#pragma unroll
      for (int jj = 0; jj < 2; ++jj)
#pragma unroll
        for (int ks = 0; ks < 2; ++ks)
          acc[ii][jj] = __builtin_amdgcn_mfma_f32_16x16x32_bf16(a[ii][ks], b[jj][ks], acc[ii][jj], 0, 0, 0);
    __builtin_amdgcn_s_setprio(0);
    __builtin_amdgcn_s_setprio(1);
#pragma unroll
    for (int ii = 0; ii < 4; ++ii)
#pragma unroll
      for (int jj = 2; jj < 4; ++jj)
#pragma unroll
        for (int ks = 0; ks < 2; ++ks)
          acc[ii][jj] = __builtin_amdgcn_mfma_f32_16x16x32_bf16(a[ii][ks], b[jj][ks], acc[ii][jj], 0, 0, 0);
    __builtin_amdgcn_s_setprio(0);
#pragma unroll
    for (int ii = 0; ii < 4; ++ii)
#pragma unroll
      for (int ks = 0; ks < 2; ++ks)
        a[ii][ks] = LDF(A, wr * 128 + 64 + ii * 16 + fr, ks);
    __builtin_amdgcn_s_setprio(1);
#pragma unroll
    for (int ii = 0; ii < 4; ++ii)
#pragma unroll
      for (int jj = 2; jj < 4; ++jj)
#pragma unroll
        for (int ks = 0; ks < 2; ++ks)
          acc[4 + ii][jj] = __builtin_amdgcn_mfma_f32_16x16x32_bf16(a[ii][ks], b[jj][ks], acc[4 + ii][jj], 0, 0, 0);
    __builtin_amdgcn_s_setprio(0);
    __builtin_amdgcn_s_setprio(1);
#pragma unroll
    for (int ii = 0; ii < 4; ++ii)
#pragma unroll
      for (int jj = 0; jj < 2; ++jj)
#pragma unroll
        for (int ks = 0; ks < 2; ++ks)
          acc[4 + ii][jj] = __builtin_amdgcn_mfma_f32_16x16x32_bf16(a[ii][ks], b[jj][ks], acc[4 + ii][jj], 0, 0, 0);
    __builtin_amdgcn_s_setprio(0);
    asm volatile("s_barrier" ::: "memory");   // all reads of dbuf d done
    if (T < 14) SC_STAGE(T + 2, d);           // prefetch tile T+2 into dbuf d
  }
#undef LDF
#undef SC_STAGE

  // epilogue: partial over this wave's 64-wide wc slice (fast_tanh), then
  // LDS-reduce across the 4 wc waves, plain store to plane nt.
  int b = m0 >> 9;
  if (t < 256) { dh_s[t] = dh[b * HID + n0 + t]; v_s[t] = v[n0 + t]; }
  __syncthreads();
  float sp[32];
#pragma unroll
  for (int q = 0; q < 32; ++q) sp[q] = 0.f;
#pragma unroll
  for (int ii = 0; ii < 8; ++ii)
#pragma unroll
    for (int jj = 0; jj < 4; ++jj) {
      int nl = wc * 64 + jj * 16 + fr;
      float dv = dh_s[nl], vv = v_s[nl];
#pragma unroll
      for (int r = 0; r < 4; ++r)
        sp[ii * 4 + r] += fast_tanh(dv + acc[ii][jj][r]) * vv;
    }
#pragma unroll
  for (int q = 0; q < 32; ++q) {
    float x = sp[q];
    x += __shfl_xor(x, 1);
    x += __shfl_xor(x, 2);
    x += __shfl_xor(x, 4);
    x += __shfl_xor(x, 8);
    sp[q] = x;
  }
  if (fr == 0) {
    int rl = wr * 128 + (l >> 4) * 4;   // local row base
#pragma unroll
    for (int ii = 0; ii < 8; ++ii)
#pragma unroll
      for (int r = 0; r < 4; ++r)
        red4[wc][rl + ii * 16 + r] = sp[ii * 4 + r];
  }
  __syncthreads();
  if (t < 256)
    spart[nt * 32768 + m0 + t] = red4[0][t] + red4[1][t] + red4[2][t] + red4[3][t];
}

// ---- softmax over S per batch row (sums 4 nt planes) + zero ctx ----
__global__ void softmax_kernel(const float* __restrict__ spart, float* __restrict__ attn,
                               float* __restrict__ ctx) {
  __shared__ float red[8];
  int b = blockIdx.x, t = threadIdx.x;  // 512 threads
  int row = b * SEQ + t;
  float x = spart[row] + spart[32768 + row] + spart[65536 + row] + spart[98304 + row];
  float m = x;
  for (int d = 1; d < 64; d <<= 1) m = fmaxf(m, __shfl_xor(m, d));
  if ((t & 63) == 0) red[t >> 6] = m;
  __syncthreads();
  float bm = red[0];
#pragma unroll
  for (int i = 1; i < 8; i++) bm = fmaxf(bm, red[i]);
  float e = expf(x - bm);
  float s = e;
  for (int d = 1; d < 64; d <<= 1) s += __shfl_xor(s, d);
  __syncthreads();
  if ((t & 63) == 0) red[t >> 6] = s;
  __syncthreads();
  float bs = 0.f;
#pragma unroll
  for (int i = 0; i < 8; i++) bs += red[i];
  attn[b * SEQ + t] = e / bs;
  // zero ctx (atomic target of context2, which runs next)
  ctx[b * HID + t] = 0.f;
  ctx[b * HID + 512 + t] = 0.f;
}

// ------- context: bf16 enc, 16B/lane; ctx[b,h] = sum_s attn[b,s]*enc[b,s,h] -------
__global__ void context2_kernel(const unsigned short* __restrict__ encb,
                                const float* __restrict__ attn, float* __restrict__ ctx) {
  __shared__ float a_s[64];
  int b = blockIdx.y, s0 = blockIdx.x * 64, t = threadIdx.x;
  if (t < 64) a_s[t] = attn[b * SEQ + s0 + t];
  __syncthreads();
  int hg = (t & 127) * 8, sg = (t >> 7) * 32;  // 128 h-threads x 2 s-groups
  float a0 = 0.f, a1 = 0.f, a2 = 0.f, a3 = 0.f, a4 = 0.f, a5 = 0.f, a6 = 0.f, a7 = 0.f;
  const unsigned short* base = encb + ((size_t)b * SEQ + s0 + sg) * HID + hg;
  for (int s = 0; s < 32; s++) {
    uint4 ev = *(const uint4*)(base + (size_t)s * HID);
    float a = a_s[sg + s];
    a0 += a * bf2f(ev.x & 0xffffu); a1 += a * bf2f(ev.x >> 16);
    a2 += a * bf2f(ev.y & 0xffffu); a3 += a * bf2f(ev.y >> 16);
    a4 += a * bf2f(ev.z & 0xffffu); a5 += a * bf2f(ev.z >> 16);
    a6 += a * bf2f(ev.w & 0xffffu); a7 += a * bf2f(ev.w >> 16);
  }
  atomicAdd(&ctx[b * HID + hg + 0], a0);
  atomicAdd(&ctx[b * HID + hg + 1], a1);
  atomicAdd(&ctx[b * HID + hg + 2], a2);
  atomicAdd(&ctx[b * HID + hg + 3], a3);
  atomicAdd(&ctx[b * HID + hg + 4], a4);
  atomicAdd(&ctx[b * HID + hg + 5], a5);
  atomicAdd(&ctx[b * HID + hg + 6], a6);
  atomicAdd(&ctx[b * HID + hg + 7], a7);
}

// ==== gates via MFMA: gpart[kz] = x @ W[:, kz*320:+320]^T  (M=64, N=4096) ====
__launch_bounds__(256)
__global__ void gates8p_kernel(const int* __restrict__ tok, const float* __restrict__ emb,
                               const float* __restrict__ ctx, const float* __restrict__ h0,
                               const float* __restrict__ W_ih, const float* __restrict__ W_hh,
                               float* __restrict__ gpart) {
  __shared__ __align__(16) unsigned short lA[64 * 40];
  __shared__ __align__(16) unsigned short lB[128 * 40];
  int n0 = blockIdx.x * 128, kz = blockIdx.y;   // 32 n-blocks x 8 K-slices
  int kbase = kz * 320;
  int t = threadIdx.x, w = t >> 6, l = t & 63;
  f32x4 acc[4][2];
#pragma unroll
  for (int i = 0; i < 4; i++)
#pragma unroll
    for (int j = 0; j < 2; j++) acc[i][j] = (f32x4){0.f, 0.f, 0.f, 0.f};
  int rowA = t >> 2, qA = (t & 3) * 8;   // 64 rows x 4 quads of 8
  int rowB = t >> 1, hB = t & 1;         // 128 rows x 2 halves of 16
  int tkA = tok[rowA];

  for (int kt = 0; kt < 10; kt++) {
    int k0 = kbase + kt * 32;
    {  // A stage (segments never cross 512/1536)
      int kg = k0 + qA;
      const float* src;
      if (kg < 512)        src = emb + (size_t)tkA * EMBED + kg;
      else if (kg < 1536)  src = ctx + rowA * HID + (kg - 512);
      else                 src = h0 + rowA * HID + (kg - 1536);
      float4 f0 = *(const float4*)src;
      float4 f1 = *(const float4*)(src + 4);
      union { unsigned short us[8]; uint4 u; } p;
      p.us[0]=f2bf(f0.x); p.us[1]=f2bf(f0.y); p.us[2]=f2bf(f0.z); p.us[3]=f2bf(f0.w);
      p.us[4]=f2bf(f1.x); p.us[5]=f2bf(f1.y); p.us[6]=f2bf(f1.z); p.us[7]=f2bf(f1.w);
      *(uint4*)&lA[rowA * 40 + qA] = p.u;
    }
    {  // B stage (16-seg never crosses 1536)
      int kg = k0 + hB * 16;
      const float* src = (kg < 1536) ? (W_ih + (size_t)(n0 + rowB) * 1536 + kg)
                                     : (W_hh + (size_t)(n0 + rowB) * 1024 + (kg - 1536));
      float4 f0 = *(const float4*)src;
      float4 f1 = *(const float4*)(src + 4);
      float4 f2 = *(const float4*)(src + 8);
      float4 f3 = *(const float4*)(src + 12);
      union { unsigned short us[16]; uint4 u4[2]; } p;
      p.us[0]=f2bf(f0.x);  p.us[1]=f2bf(f0.y);  p.us[2]=f2bf(f0.z);  p.us[3]=f2bf(f0.w);
      p.us[4]=f2bf(f1.x);  p.us[5]=f2bf(f1.y);  p.us[6]=f2bf(f1.z);  p.us[7]=f2bf(f1.w);
      p.us[8]=f2bf(f2.x);  p.us[9]=f2bf(f2.y);  p.us[10]=f2bf(f2.z); p.us[11]=f2bf(f2.w);
      p.us[12]=f2bf(f3.x); p.us[13]=f2bf(f3.y); p.us[14]=f2bf(f3.z); p.us[15]=f2bf(f3.w);
      *(uint4*)&lB[rowB * 40 + hB * 16 + 0] = p.u4[0];
      *(uint4*)&lB[rowB * 40 + hB * 16 + 8] = p.u4[1];
    }
    __syncthreads();
    bf16x8 af[4], bv[2];
    int co = (l >> 4) * 8;
#pragma unroll
    for (int i = 0; i < 4; i++) af[i] = *(const bf16x8*)&lA[(i * 16 + (l & 15)) * 40 + co];
#pragma unroll
    for (int j = 0; j < 2; j++) bv[j] = *(const bf16x8*)&lB[(w * 32 + j * 16 + (l & 15)) * 40 + co];
#pragma unroll
    for (int i = 0; i < 4; i++)
#pragma unroll
      for (int j = 0; j < 2; j++)
        acc[i][j] = __builtin_amdgcn_mfma_f32_16x16x32_bf16(af[i], bv[j], acc[i][j], 0, 0, 0);
    __syncthreads();
  }
#pragma unroll
  for (int i = 0; i < 4; i++)
#pragma unroll
    for (int j = 0; j < 2; j++) {
      int n = n0 + w * 32 + j * 16 + (l & 15);
#pragma unroll
      for (int r = 0; r < 4; r++) {
        int m = i * 16 + (l >> 4) * 4 + r;
        gpart[(size_t)kz * 262144 + (size_t)m * 4096 + n] = acc[i][j][r];
      }
    }
}

// ------- LSTM pointwise (fused 8-plane gate combine) -> h1, c1 -------
__global__ void lstm_kernel(const float* __restrict__ gpart, const float* __restrict__ b_ih,
                            const float* __restrict__ b_hh, const float* __restrict__ c0,
                            float* __restrict__ out) {
  int b = blockIdx.y;
  int hh = blockIdx.x * 256 + threadIdx.x;
  float gi = b_ih[hh]        + b_hh[hh];
  float gf = b_ih[1024 + hh] + b_hh[1024 + hh];
  float gg = b_ih[2048 + hh] + b_hh[2048 + hh];
  float go = b_ih[3072 + hh] + b_hh[3072 + hh];
#pragma unroll
  for (int kz = 0; kz < 8; kz++) {
    const float* g = gpart + (size_t)kz * 262144 + (size_t)b * 4096;
    gi += g[hh];
    gf += g[1024 + hh];
    gg += g[2048 + hh];
    go += g[3072 + hh];
  }
  float si = 1.f / (1.f + expf(-gi));
  float sf = 1.f / (1.f + expf(-gf));
  float so = 1.f / (1.f + expf(-go));
  float c1 = sf * c0[b * HID + hh] + si * tanhf(gg);
  float h1 = so * tanhf(c1);
  out[OUT_H1 + b * HID + hh] = h1;
  out[OUT_C1 + b * HID + hh] = c1;
}

// ---- fc: 64-wide N-tiles x 2 K-halves = 1000 blocks (~4/CU) for HBM streaming ----
// part[kz][m][n] = A_kz[m,:] . fcW[n, kz*1024:+1024]
__launch_bounds__(256)
__global__ void fc64_kernel(const float* __restrict__ h1, const float* __restrict__ ctx,
                            const float* __restrict__ fcW, float* __restrict__ part) {
  __shared__ __align__(16) unsigned short lA[64 * 40];
  __shared__ __align__(16) unsigned short lB[64 * 40];
  int n0 = blockIdx.x * 64, kz = blockIdx.y;
  const float* A = kz ? ctx : h1;
  int t = threadIdx.x, w = t >> 6, l = t & 63;
  int fr = l & 15;
  f32x4 acc[4];
#pragma unroll
  for (int i = 0; i < 4; i++) acc[i] = (f32x4){0.f, 0.f, 0.f, 0.f};
  int rowS = t >> 2, qS = (t & 3) * 8;   // 64 rows x 4 quads of 8 (both A and B)

  for (int kt = 0; kt < 32; kt++) {
    int k0 = kt * 32;
    {  // A stage: 8 f32 -> bf16
      const float* src = A + rowS * HID + k0 + qS;
      float4 f0 = *(const float4*)src;
      float4 f1 = *(const float4*)(src + 4);
      union { unsigned short us[8]; uint4 u; } p;
      p.us[0]=f2bf(f0.x); p.us[1]=f2bf(f0.y); p.us[2]=f2bf(f0.z); p.us[3]=f2bf(f0.w);
      p.us[4]=f2bf(f1.x); p.us[5]=f2bf(f1.y); p.us[6]=f2bf(f1.z); p.us[7]=f2bf(f1.w);
      *(uint4*)&lA[rowS * 40 + qS] = p.u;
    }
    {  // B stage: 8 f32 -> bf16
      const float* src = fcW + (size_t)(n0 + rowS) * 2048 + kz * 1024 + k0 + qS;
      float4 f0 = *(const float4*)src;
      float4 f1 = *(const float4*)(src + 4);
      union { unsigned short us[8]; uint4 u; } p;
      p.us[0]=f2bf(f0.x); p.us[1]=f2bf(f0.y); p.us[2]=f2bf(f0.z); p.us[3]=f2bf(f0.w);
      p.us[4]=f2bf(f1.x); p.us[5]=f2bf(f1.y); p.us[6]=f2bf(f1.z); p.us[7]=f2bf(f1.w);
      *(uint4*)&lB[rowS * 40 + qS] = p.u;
    }
    __syncthreads();
    bf16x8 af[4], bv;
    int co = (l >> 4) * 8;
#pragma unroll
    for (int i = 0; i < 4; i++) af[i] = *(const bf16x8*)&lA[(i * 16 + fr) * 40 + co];
    bv = *(const bf16x8*)&lB[(w * 16 + fr) * 40 + co];
#pragma unroll
    for (int i = 0; i < 4; i++)
      acc[i] = __builtin_amdgcn_mfma_f32_16x16x32_bf16(af[i], bv, acc[i], 0, 0, 0);
    __syncthreads();
  }
#pragma unroll
  for (int i = 0; i < 4; i++) {
    int n = n0 + w * 16 + fr;
#pragma unroll
    for (int r = 0; r < 4; r++) {
      int m = i * 16 + (l >> 4) * 4 + r;
      part[(size_t)kz * 2048000 + (size_t)m * VOCAB + n] = acc[i][r];
    }
  }
}

// ---- combine: pred = part0 + part1 + bias, float4 ----
__global__ void fc_combine_kernel(const float* __restrict__ part,
                                  const float* __restrict__ fcb, float* __restrict__ pred) {
  int i = blockIdx.x * 256 + threadIdx.x;   // 2000*256 = 512000 float4s
  int m = i / 8000, n4 = i % 8000;
  size_t e = (size_t)m * VOCAB + n4 * 4;
  float4 p0 = *(const float4*)(part + e);
  float4 p1 = *(const float4*)(part + 2048000 + e);
  float4 bb = *(const float4*)(fcb + n4 * 4);
  float4 o;
  o.x = p0.x + p1.x + bb.x;
  o.y = p0.y + p1.y + bb.y;
  o.z = p0.z + p1.z + bb.z;
  o.w = p0.w + p1.w + bb.w;
  *(float4*)(pred + e) = o;
}

extern "C" void kernel_launch(void* const* d_in, const int* in_sizes, int n_in,
                              void* d_out, int out_size, void* d_ws, size_t ws_size,
                              hipStream_t stream) {
  const int*   tok  = (const int*)d_in[0];
  const float* h    = (const float*)d_in[1];
  const float* c    = (const float*)d_in[2];
  const float* enc  = (const float*)d_in[3];
  const float* emb  = (const float*)d_in[4];
  const float* W1   = (const float*)d_in[5];
  const float* W2   = (const float*)d_in[6];
  const float* v    = (const float*)d_in[7];
  const float* W_ih = (const float*)d_in[8];
  const float* W_hh = (const float*)d_in[9];
  const float* b_ih = (const float*)d_in[10];
  const float* b_hh = (const float*)d_in[11];
  const float* fcW  = (const float*)d_in[12];
  const float* fcb  = (const float*)d_in[13];
  float* out = (float*)d_out;

  float* wsf    = (float*)d_ws;
  float* spart  = wsf;             // 4*32768 = 131072
  float* ctx    = wsf + 131072;    // 65536
  float* dh     = wsf + 196608;    // 65536
  float* gpart  = wsf + 262144;    // 8*262144 = 2097152
  float* part   = wsf + 2359296;   // 2*2048000 = 4096000
  unsigned short* encb = (unsigned short*)(wsf + 6455296);   // 33,554,432 bf16
  unsigned short* W2b  = encb + (size_t)BATCH * SEQ * HID;   //  1,048,576 bf16

  f2bf_kernel<<<2048, 256, 0, stream>>>(enc, encb, BATCH * SEQ * HID / 8);
  dh_w2_kernel<<<768, 256, 0, stream>>>(h, W1, dh, W2, W2b);
  scores8_kernel<<<512, 512, 0, stream>>>(encb, W2b, dh, v, spart);
  softmax_kernel<<<64, 512, 0, stream>>>(spart, out + OUT_ATTN, ctx);
  context2_kernel<<<dim3(8, 64), 256, 0, stream>>>(encb, out + OUT_ATTN, ctx);
  gates8p_kernel<<<dim3(32, 8), 256, 0, stream>>>(tok, emb, ctx, h, W_ih, W_hh, gpart);
  lstm_kernel<<<dim3(4, 64), 256, 0, stream>>>(gpart, b_ih, b_hh, c, out);
  fc64_kernel<<<dim3(500, 2), 256, 0, stream>>>(out + OUT_H1, ctx, fcW, part);
  fc_combine_kernel<<<2000, 256, 0, stream>>>(part, fcb, out);
}

// Round 13
// 263.123 us; speedup vs baseline: 1.3167x; 1.0308x over previous
//
#include <hip/hip_runtime.h>
#include <math.h>

#define VOCAB 32000
#define EMBED 512
#define HID   1024
#define BATCH 64
#define SEQ   512

// d_out layout (floats): pred[64*32000]=0 .. 2048000 ; h1 @2048000 ; c1 @2113536 ; attn @2179072
#define OUT_H1   2048000
#define OUT_C1   2113536
#define OUT_ATTN 2179072

typedef __bf16 bf16x8 __attribute__((ext_vector_type(8)));
typedef float  f32x4  __attribute__((ext_vector_type(4)));

__device__ __forceinline__ unsigned short f2bf(float f) {
  unsigned int u = __builtin_bit_cast(unsigned int, f);
  u += 0x7fffu + ((u >> 16) & 1u);   // round-to-nearest-even
  return (unsigned short)(u >> 16);
}
__device__ __forceinline__ float bf2f(unsigned int u) {
  return __builtin_bit_cast(float, u << 16);
}

// fast tanh: (e^{2x}-1)/(e^{2x}+1) via hw exp2; clamp avoids inf/inf
__device__ __forceinline__ float fast_tanh(float x) {
  float cx = fminf(fmaxf(x, -15.f), 15.f);
  float t = __builtin_amdgcn_exp2f(cx * 2.8853900817779268f);  // e^{2x}
  return (t - 1.f) / (t + 1.f);
}

// async 16B/lane global->LDS; lds ptr must be wave-uniform (HW: base + lane*16)
__device__ __forceinline__ void gload16(const unsigned short* g, unsigned short* l) {
  __builtin_amdgcn_global_load_lds(
      (const __attribute__((address_space(1))) void*)g,
      (__attribute__((address_space(3))) void*)l, 16, 0, 0);
}

// ------------- f32 -> bf16 bulk convert (grid-stride, 8 elems/thread/iter) -------------
__global__ void f2bf_kernel(const float* __restrict__ src, unsigned short* __restrict__ dst,
                            int n8) {
  int i = blockIdx.x * blockDim.x + threadIdx.x;
  int stride = gridDim.x * blockDim.x;
  for (; i < n8; i += stride) {
    const float* s = src + (size_t)i * 8;
    float4 f0 = *(const float4*)s;
    float4 f1 = *(const float4*)(s + 4);
    union { unsigned short us[8]; uint4 u; } p;
    p.us[0]=f2bf(f0.x); p.us[1]=f2bf(f0.y); p.us[2]=f2bf(f0.z); p.us[3]=f2bf(f0.w);
    p.us[4]=f2bf(f1.x); p.us[5]=f2bf(f1.y); p.us[6]=f2bf(f1.z); p.us[7]=f2bf(f1.w);
    *(uint4*)(dst + (size_t)i * 8) = p.u;
  }
}

// ---- dh = h0 @ W1^T (blocks 0..255) + W2 f32->bf16 (blocks 256..767) ----
__global__ void dh_w2_kernel(const float* __restrict__ h0, const float* __restrict__ W1,
                             float* __restrict__ dh,
                             const float* __restrict__ W2, unsigned short* __restrict__ W2b) {
  __shared__ float hs[HID];
  int bid = blockIdx.x, t = threadIdx.x;
  if (bid < 256) {
    int b = bid >> 2, kblk = bid & 3;
    for (int i = t; i < HID; i += 256) hs[i] = h0[b * HID + i];
    __syncthreads();
    int k = kblk * 256 + t;
    const float* w = W1 + (size_t)k * HID;
    float acc = 0.f;
    for (int hh = 0; hh < HID; hh += 4) {
      float4 wv = *(const float4*)(w + hh);
      float4 hv = *(const float4*)(hs + hh);
      acc += wv.x * hv.x + wv.y * hv.y + wv.z * hv.z + wv.w * hv.w;
    }
    dh[b * HID + k] = acc;
  } else {
    int i = (bid - 256) * 256 + t;   // 512*256 = 131072 groups of 8 = HID*HID/8
    const float* s = W2 + (size_t)i * 8;
    float4 f0 = *(const float4*)s;
    float4 f1 = *(const float4*)(s + 4);
    union { unsigned short us[8]; uint4 u; } p;
    p.us[0]=f2bf(f0.x); p.us[1]=f2bf(f0.y); p.us[2]=f2bf(f0.z); p.us[3]=f2bf(f0.w);
    p.us[4]=f2bf(f1.x); p.us[5]=f2bf(f1.y); p.us[6]=f2bf(f1.z); p.us[7]=f2bf(f1.w);
    *(uint4*)(W2b + (size_t)i * 8) = p.u;
  }
}

// ==== scores: 256x256 tile, BK=64, 8 waves, counted-vmcnt pipeline ====
// Epilogue: in-block wc-reduction via LDS, plain store into 4 nt partial
// planes (no atomics, no pre-zero). spart[nt*32768 + global_row].
__launch_bounds__(512, 2)
__global__ void scores8_kernel(const unsigned short* __restrict__ encb,
                               const unsigned short* __restrict__ W2b,
                               const float* __restrict__ dh, const float* __restrict__ v,
                               float* __restrict__ spart) {
  __shared__ __align__(16) unsigned short sA[2][16384];  // [dbuf][256 rows * 64 k]
  __shared__ __align__(16) unsigned short sB[2][16384];
  __shared__ float dh_s[256];
  __shared__ float v_s[256];
  __shared__ float red4[4][256];

  int bid = blockIdx.x;
  int wg = (bid & 7) * 64 + (bid >> 3);
  int mt = wg >> 2, nt = wg & 3;
  int m0 = mt * 256, n0 = nt * 256;

  int t = threadIdx.x;
  int wid = t >> 6, l = t & 63;
  int wr = wid >> 2, wc = wid & 3;     // 2 M-waves x 4 N-waves
  int fr = l & 15, co = (l >> 4) * 8;

  // Stage-source for the (row&7)<<3 elem-swizzle (r11-verified)
  const unsigned short* pa0;
  const unsigned short* pb0;
  int do0 = wid * 512;
  {
    int row0 = wid * 8 + (l >> 3);
    int colE = ((l & 7) ^ ((l >> 3) & 7)) << 3;
    pa0 = encb + (size_t)(m0 + row0) * HID + colE;
    pb0 = W2b + (size_t)(n0 + row0) * HID + colE;
  }

  f32x4 acc[8][4];
#pragma unroll
  for (int i = 0; i < 8; i++)
#pragma unroll
    for (int j = 0; j < 4; j++) acc[i][j] = (f32x4){0.f, 0.f, 0.f, 0.f};

#define SC_STAGE(T, d)                                                         \
  do {                                                                         \
    int k0_ = (T) * 64;                                                        \
    gload16(pa0 + k0_,          &sA[d][do0]);                                  \
    gload16(pa0 + 65536 + k0_,  &sA[d][do0 + 4096]);                           \
    gload16(pa0 + 131072 + k0_, &sA[d][do0 + 8192]);                           \
    gload16(pa0 + 196608 + k0_, &sA[d][do0 + 12288]);                          \
    gload16(pb0 + k0_,          &sB[d][do0]);                                  \
    gload16(pb0 + 65536 + k0_,  &sB[d][do0 + 4096]);                           \
    gload16(pb0 + 131072 + k0_, &sB[d][do0 + 8192]);                           \
    gload16(pb0 + 196608 + k0_, &sB[d][do0 + 12288]);                          \
  } while (0)

  SC_STAGE(0, 0);
  SC_STAGE(1, 1);

  // swizzled ds_read: elem col ^= (row&7)<<3
#define LDF(Mat, row, ks) \
  (*(const bf16x8*)&Mat[(row) * 64 + (((ks) * 32 + co) ^ (((row) & 7) << 3))])

  for (int T = 0; T < 16; ++T) {
    int d = T & 1;
    if (T == 15) asm volatile("s_waitcnt vmcnt(0)" ::: "memory");
    else         asm volatile("s_waitcnt vmcnt(8)" ::: "memory");
    asm volatile("s_barrier" ::: "memory");
    const unsigned short* A = sA[d];
    const unsigned short* B = sB[d];
    bf16x8 a[4][2], b[4][2];
#pragma unroll
    for (int jj = 0; jj < 4; ++jj)
#pragma unroll
      for (int ks = 0; ks < 2; ++ks)
        b[jj][ks] = LDF(B, wc * 64 + jj * 16 + fr, ks);
#pragma unroll
    for (int ii = 0; ii < 4; ++ii)
#pragma unroll
      for (int ks = 0; ks < 2; ++ks)
        a[ii][ks] = LDF(A, wr * 128 + ii * 16 + fr, ks);
    __builtin_amdgcn_s_setprio(1);
#pragma unroll
    for (int ii = 0; ii < 4; ++ii)
#pragma unroll
      for (int jj = 0; jj < 2; ++jj)
#pragma unroll
        for (int ks = 0; ks < 2; ++ks)
          acc[ii][jj] = __builtin_amdgcn_mfma_f32_16x16x32_bf16(a[ii][ks], b[jj][ks], acc[ii][jj], 0, 0, 0);
    __builtin_amdgcn_s_setprio(0);
    __builtin_amdgcn_s_setprio(1);
#pragma unroll
    for (int ii = 0; ii < 4; ++ii)
#pragma unroll
      for (int jj = 2; jj < 4; ++jj)
#pragma unroll
        for (int ks = 0; ks < 2; ++ks)
          acc[ii][jj] = __builtin_amdgcn_mfma_f32_16x16x32_bf16(a[ii][ks], b[jj][ks], acc[ii][jj], 0, 0, 0);
    __builtin_amdgcn_s_setprio(0);
#pragma unroll
    for (int ii = 0; ii < 4; ++ii)
#pragma unroll
      for (int ks = 0; ks < 2; ++ks)
        a[ii][ks] = LDF(A, wr * 128 + 64 + ii * 16 + fr, ks);
    __builtin_amdgcn_s_setprio(1);
#pragma unroll
    for (int ii = 0; ii < 4; ++ii)
#pragma unroll
      for (int jj = 2; jj < 4; ++jj)
#pragma unroll
        for (int ks = 0; ks < 2; ++ks)
          acc[4 + ii][jj] = __builtin_amdgcn_mfma_f32_16x16x32_bf16(a[ii][ks], b[jj][ks], acc[4 + ii][jj], 0, 0, 0);
    __builtin_amdgcn_s_setprio(0);
    __builtin_amdgcn_s_setprio(1);
#pragma unroll
    for (int ii = 0; ii < 4; ++ii)
#pragma unroll
      for (int jj = 0; jj < 2; ++jj)
#pragma unroll
        for (int ks = 0; ks < 2; ++ks)
          acc[4 + ii][jj] = __builtin_amdgcn_mfma_f32_16x16x32_bf16(a[ii][ks], b[jj][ks], acc[4 + ii][jj], 0, 0, 0);
    __builtin_amdgcn_s_setprio(0);
    asm volatile("s_barrier" ::: "memory");   // all reads of dbuf d done
    if (T < 14) SC_STAGE(T + 2, d);           // prefetch tile T+2 into dbuf d
  }
#undef LDF
#undef SC_STAGE

  // epilogue: partial over this wave's 64-wide wc slice (fast_tanh), then
  // LDS-reduce across the 4 wc waves, plain store to plane nt.
  int b = m0 >> 9;
  if (t < 256) { dh_s[t] = dh[b * HID + n0 + t]; v_s[t] = v[n0 + t]; }
  __syncthreads();
  float sp[32];
#pragma unroll
  for (int q = 0; q < 32; ++q) sp[q] = 0.f;
#pragma unroll
  for (int ii = 0; ii < 8; ++ii)
#pragma unroll
    for (int jj = 0; jj < 4; ++jj) {
      int nl = wc * 64 + jj * 16 + fr;
      float dv = dh_s[nl], vv = v_s[nl];
#pragma unroll
      for (int r = 0; r < 4; ++r)
        sp[ii * 4 + r] += fast_tanh(dv + acc[ii][jj][r]) * vv;
    }
#pragma unroll
  for (int q = 0; q < 32; ++q) {
    float x = sp[q];
    x += __shfl_xor(x, 1);
    x += __shfl_xor(x, 2);
    x += __shfl_xor(x, 4);
    x += __shfl_xor(x, 8);
    sp[q] = x;
  }
  if (fr == 0) {
    int rl = wr * 128 + (l >> 4) * 4;   // local row base
#pragma unroll
    for (int ii = 0; ii < 8; ++ii)
#pragma unroll
      for (int r = 0; r < 4; ++r)
        red4[wc][rl + ii * 16 + r] = sp[ii * 4 + r];
  }
  __syncthreads();
  if (t < 256)
    spart[nt * 32768 + m0 + t] = red4[0][t] + red4[1][t] + red4[2][t] + red4[3][t];
}

// ---- softmax over S per batch row (sums 4 nt planes) + zero ctx ----
__global__ void softmax_kernel(const float* __restrict__ spart, float* __restrict__ attn,
                               float* __restrict__ ctx) {
  __shared__ float red[8];
  int b = blockIdx.x, t = threadIdx.x;  // 512 threads
  int row = b * SEQ + t;
  float x = spart[row] + spart[32768 + row] + spart[65536 + row] + spart[98304 + row];
  float m = x;
  for (int d = 1; d < 64; d <<= 1) m = fmaxf(m, __shfl_xor(m, d));
  if ((t & 63) == 0) red[t >> 6] = m;
  __syncthreads();
  float bm = red[0];
#pragma unroll
  for (int i = 1; i < 8; i++) bm = fmaxf(bm, red[i]);
  float e = expf(x - bm);
  float s = e;
  for (int d = 1; d < 64; d <<= 1) s += __shfl_xor(s, d);
  __syncthreads();
  if ((t & 63) == 0) red[t >> 6] = s;
  __syncthreads();
  float bs = 0.f;
#pragma unroll
  for (int i = 0; i < 8; i++) bs += red[i];
  attn[b * SEQ + t] = e / bs;
  // zero ctx (atomic target of context2, which runs next)
  ctx[b * HID + t] = 0.f;
  ctx[b * HID + 512 + t] = 0.f;
}

// ------- context: bf16 enc, 16B/lane; ctx[b,h] = sum_s attn[b,s]*enc[b,s,h] -------
__global__ void context2_kernel(const unsigned short* __restrict__ encb,
                                const float* __restrict__ attn, float* __restrict__ ctx) {
  __shared__ float a_s[64];
  int b = blockIdx.y, s0 = blockIdx.x * 64, t = threadIdx.x;
  if (t < 64) a_s[t] = attn[b * SEQ + s0 + t];
  __syncthreads();
  int hg = (t & 127) * 8, sg = (t >> 7) * 32;  // 128 h-threads x 2 s-groups
  float a0 = 0.f, a1 = 0.f, a2 = 0.f, a3 = 0.f, a4 = 0.f, a5 = 0.f, a6 = 0.f, a7 = 0.f;
  const unsigned short* base = encb + ((size_t)b * SEQ + s0 + sg) * HID + hg;
  for (int s = 0; s < 32; s++) {
    uint4 ev = *(const uint4*)(base + (size_t)s * HID);
    float a = a_s[sg + s];
    a0 += a * bf2f(ev.x & 0xffffu); a1 += a * bf2f(ev.x >> 16);
    a2 += a * bf2f(ev.y & 0xffffu); a3 += a * bf2f(ev.y >> 16);
    a4 += a * bf2f(ev.z & 0xffffu); a5 += a * bf2f(ev.z >> 16);
    a6 += a * bf2f(ev.w & 0xffffu); a7 += a * bf2f(ev.w >> 16);
  }
  atomicAdd(&ctx[b * HID + hg + 0], a0);
  atomicAdd(&ctx[b * HID + hg + 1], a1);
  atomicAdd(&ctx[b * HID + hg + 2], a2);
  atomicAdd(&ctx[b * HID + hg + 3], a3);
  atomicAdd(&ctx[b * HID + hg + 4], a4);
  atomicAdd(&ctx[b * HID + hg + 5], a5);
  atomicAdd(&ctx[b * HID + hg + 6], a6);
  atomicAdd(&ctx[b * HID + hg + 7], a7);
}

// ==== gates via MFMA: gpart[kz] = x @ W[:, kz*320:+320]^T  (M=64, N=4096) ====
__launch_bounds__(256)
__global__ void gates8p_kernel(const int* __restrict__ tok, const float* __restrict__ emb,
                               const float* __restrict__ ctx, const float* __restrict__ h0,
                               const float* __restrict__ W_ih, const float* __restrict__ W_hh,
                               float* __restrict__ gpart) {
  __shared__ __align__(16) unsigned short lA[64 * 40];
  __shared__ __align__(16) unsigned short lB[128 * 40];
  int n0 = blockIdx.x * 128, kz = blockIdx.y;   // 32 n-blocks x 8 K-slices
  int kbase = kz * 320;
  int t = threadIdx.x, w = t >> 6, l = t & 63;
  f32x4 acc[4][2];
#pragma unroll
  for (int i = 0; i < 4; i++)
#pragma unroll
    for (int j = 0; j < 2; j++) acc[i][j] = (f32x4){0.f, 0.f, 0.f, 0.f};
  int rowA = t >> 2, qA = (t & 3) * 8;   // 64 rows x 4 quads of 8
  int rowB = t >> 1, hB = t & 1;         // 128 rows x 2 halves of 16
  int tkA = tok[rowA];

  for (int kt = 0; kt < 10; kt++) {
    int k0 = kbase + kt * 32;
    {  // A stage (segments never cross 512/1536)
      int kg = k0 + qA;
      const float* src;
      if (kg < 512)        src = emb + (size_t)tkA * EMBED + kg;
      else if (kg < 1536)  src = ctx + rowA * HID + (kg - 512);
      else                 src = h0 + rowA * HID + (kg - 1536);
      float4 f0 = *(const float4*)src;
      float4 f1 = *(const float4*)(src + 4);
      union { unsigned short us[8]; uint4 u; } p;
      p.us[0]=f2bf(f0.x); p.us[1]=f2bf(f0.y); p.us[2]=f2bf(f0.z); p.us[3]=f2bf(f0.w);
      p.us[4]=f2bf(f1.x); p.us[5]=f2bf(f1.y); p.us[6]=f2bf(f1.z); p.us[7]=f2bf(f1.w);
      *(uint4*)&lA[rowA * 40 + qA] = p.u;
    }
    {  // B stage (16-seg never crosses 1536)
      int kg = k0 + hB * 16;
      const float* src = (kg < 1536) ? (W_ih + (size_t)(n0 + rowB) * 1536 + kg)
                                     : (W_hh + (size_t)(n0 + rowB) * 1024 + (kg - 1536));
      float4 f0 = *(const float4*)src;
      float4 f1 = *(const float4*)(src + 4);
      float4 f2 = *(const float4*)(src + 8);
      float4 f3 = *(const float4*)(src + 12);
      union { unsigned short us[16]; uint4 u4[2]; } p;
      p.us[0]=f2bf(f0.x);  p.us[1]=f2bf(f0.y);  p.us[2]=f2bf(f0.z);  p.us[3]=f2bf(f0.w);
      p.us[4]=f2bf(f1.x);  p.us[5]=f2bf(f1.y);  p.us[6]=f2bf(f1.z);  p.us[7]=f2bf(f1.w);
      p.us[8]=f2bf(f2.x);  p.us[9]=f2bf(f2.y);  p.us[10]=f2bf(f2.z); p.us[11]=f2bf(f2.w);
      p.us[12]=f2bf(f3.x); p.us[13]=f2bf(f3.y); p.us[14]=f2bf(f3.z); p.us[15]=f2bf(f3.w);
      *(uint4*)&lB[rowB * 40 + hB * 16 + 0] = p.u4[0];
      *(uint4*)&lB[rowB * 40 + hB * 16 + 8] = p.u4[1];
    }
    __syncthreads();
    bf16x8 af[4], bv[2];
    int co = (l >> 4) * 8;
#pragma unroll
    for (int i = 0; i < 4; i++) af[i] = *(const bf16x8*)&lA[(i * 16 + (l & 15)) * 40 + co];
#pragma unroll
    for (int j = 0; j < 2; j++) bv[j] = *(const bf16x8*)&lB[(w * 32 + j * 16 + (l & 15)) * 40 + co];
#pragma unroll
    for (int i = 0; i < 4; i++)
#pragma unroll
      for (int j = 0; j < 2; j++)
        acc[i][j] = __builtin_amdgcn_mfma_f32_16x16x32_bf16(af[i], bv[j], acc[i][j], 0, 0, 0);
    __syncthreads();
  }
#pragma unroll
  for (int i = 0; i < 4; i++)
#pragma unroll
    for (int j = 0; j < 2; j++) {
      int n = n0 + w * 32 + j * 16 + (l & 15);
#pragma unroll
      for (int r = 0; r < 4; r++) {
        int m = i * 16 + (l >> 4) * 4 + r;
        gpart[(size_t)kz * 262144 + (size_t)m * 4096 + n] = acc[i][j][r];
      }
    }
}

// ------- LSTM pointwise (fused 8-plane gate combine) -> h1, c1 -------
__global__ void lstm_kernel(const float* __restrict__ gpart, const float* __restrict__ b_ih,
                            const float* __restrict__ b_hh, const float* __restrict__ c0,
                            float* __restrict__ out) {
  int b = blockIdx.y;
  int hh = blockIdx.x * 256 + threadIdx.x;
  float gi = b_ih[hh]        + b_hh[hh];
  float gf = b_ih[1024 + hh] + b_hh[1024 + hh];
  float gg = b_ih[2048 + hh] + b_hh[2048 + hh];
  float go = b_ih[3072 + hh] + b_hh[3072 + hh];
#pragma unroll
  for (int kz = 0; kz < 8; kz++) {
    const float* g = gpart + (size_t)kz * 262144 + (size_t)b * 4096;
    gi += g[hh];
    gf += g[1024 + hh];
    gg += g[2048 + hh];
    go += g[3072 + hh];
  }
  float si = 1.f / (1.f + expf(-gi));
  float sf = 1.f / (1.f + expf(-gf));
  float so = 1.f / (1.f + expf(-go));
  float c1 = sf * c0[b * HID + hh] + si * tanhf(gg);
  float h1 = so * tanhf(c1);
  out[OUT_H1 + b * HID + hh] = h1;
  out[OUT_C1 + b * HID + hh] = c1;
}

// ---- fc: full K=2048 per block, 500 blocks x 512 threads (8 waves = 4000 waves
// total, same TLP as r12's 1000x4), direct pred write with bias (no part/combine).
__launch_bounds__(512)
__global__ void fcK2048_kernel(const float* __restrict__ h1, const float* __restrict__ ctx,
                               const float* __restrict__ fcW, const float* __restrict__ fcb,
                               float* __restrict__ pred) {
  __shared__ __align__(16) unsigned short lA[64 * 72];  // 64 rows x 64 k, pad 72
  __shared__ __align__(16) unsigned short lB[64 * 72];
  int n0 = blockIdx.x * 64;
  int t = threadIdx.x, w = t >> 6, l = t & 63;
  int wr = w >> 2, wc = w & 3;         // 2 M-halves x 4 N-quarters
  int fr = l & 15, co = (l >> 4) * 8;
  f32x4 acc[2];
  acc[0] = (f32x4){0.f, 0.f, 0.f, 0.f};
  acc[1] = (f32x4){0.f, 0.f, 0.f, 0.f};
  int rowS = t >> 3, qS = (t & 7) * 8;   // 64 rows x 8 quads of 8 (BK=64)

  for (int kt = 0; kt < 32; kt++) {
    int k0 = kt * 64;
    {  // A stage: x = [h1 | ctx], 8-seg never crosses the 1024 boundary
      int kg = k0 + qS;
      const float* src = (kg < 1024) ? (h1 + rowS * HID + kg) : (ctx + rowS * HID + kg - 1024);
      float4 f0 = *(const float4*)src;
      float4 f1 = *(const float4*)(src + 4);
      union { unsigned short us[8]; uint4 u; } p;
      p.us[0]=f2bf(f0.x); p.us[1]=f2bf(f0.y); p.us[2]=f2bf(f0.z); p.us[3]=f2bf(f0.w);
      p.us[4]=f2bf(f1.x); p.us[5]=f2bf(f1.y); p.us[6]=f2bf(f1.z); p.us[7]=f2bf(f1.w);
      *(uint4*)&lA[rowS * 72 + qS] = p.u;
    }
    {  // B stage
      const float* src = fcW + (size_t)(n0 + rowS) * 2048 + k0 + qS;
      float4 f0 = *(const float4*)src;
      float4 f1 = *(const float4*)(src + 4);
      union { unsigned short us[8]; uint4 u; } p;
      p.us[0]=f2bf(f0.x); p.us[1]=f2bf(f0.y); p.us[2]=f2bf(f0.z); p.us[3]=f2bf(f0.w);
      p.us[4]=f2bf(f1.x); p.us[5]=f2bf(f1.y); p.us[6]=f2bf(f1.z); p.us[7]=f2bf(f1.w);
      *(uint4*)&lB[rowS * 72 + qS] = p.u;
    }
    __syncthreads();
    bf16x8 a0, a1, bv;
#pragma unroll
    for (int ks = 0; ks < 2; ks++) {
      a0 = *(const bf16x8*)&lA[(wr * 32 + fr) * 72 + ks * 32 + co];
      a1 = *(const bf16x8*)&lA[(wr * 32 + 16 + fr) * 72 + ks * 32 + co];
      bv = *(const bf16x8*)&lB[(wc * 16 + fr) * 72 + ks * 32 + co];
      acc[0] = __builtin_amdgcn_mfma_f32_16x16x32_bf16(a0, bv, acc[0], 0, 0, 0);
      acc[1] = __builtin_amdgcn_mfma_f32_16x16x32_bf16(a1, bv, acc[1], 0, 0, 0);
    }
    __syncthreads();
  }
  int n = n0 + wc * 16 + fr;
  float bias = fcb[n];
#pragma unroll
  for (int i = 0; i < 2; i++) {
#pragma unroll
    for (int r = 0; r < 4; r++) {
      int m = wr * 32 + i * 16 + (l >> 4) * 4 + r;
      pred[(size_t)m * VOCAB + n] = acc[i][r] + bias;
    }
  }
}

extern "C" void kernel_launch(void* const* d_in, const int* in_sizes, int n_in,
                              void* d_out, int out_size, void* d_ws, size_t ws_size,
                              hipStream_t stream) {
  const int*   tok  = (const int*)d_in[0];
  const float* h    = (const float*)d_in[1];
  const float* c    = (const float*)d_in[2];
  const float* enc  = (const float*)d_in[3];
  const float* emb  = (const float*)d_in[4];
  const float* W1   = (const float*)d_in[5];
  const float* W2   = (const float*)d_in[6];
  const float* v    = (const float*)d_in[7];
  const float* W_ih = (const float*)d_in[8];
  const float* W_hh = (const float*)d_in[9];
  const float* b_ih = (const float*)d_in[10];
  const float* b_hh = (const float*)d_in[11];
  const float* fcW  = (const float*)d_in[12];
  const float* fcb  = (const float*)d_in[13];
  float* out = (float*)d_out;

  float* wsf    = (float*)d_ws;
  float* spart  = wsf;             // 4*32768 = 131072
  float* ctx    = wsf + 131072;    // 65536
  float* dh     = wsf + 196608;    // 65536
  float* gpart  = wsf + 262144;    // 8*262144 = 2097152
  unsigned short* encb = (unsigned short*)(wsf + 2359296);   // 33,554,432 bf16
  unsigned short* W2b  = encb + (size_t)BATCH * SEQ * HID;   //  1,048,576 bf16

  f2bf_kernel<<<2048, 256, 0, stream>>>(enc, encb, BATCH * SEQ * HID / 8);
  dh_w2_kernel<<<768, 256, 0, stream>>>(h, W1, dh, W2, W2b);
  scores8_kernel<<<512, 512, 0, stream>>>(encb, W2b, dh, v, spart);
  softmax_kernel<<<64, 512, 0, stream>>>(spart, out + OUT_ATTN, ctx);
  context2_kernel<<<dim3(8, 64), 256, 0, stream>>>(encb, out + OUT_ATTN, ctx);
  gates8p_kernel<<<dim3(32, 8), 256, 0, stream>>>(tok, emb, ctx, h, W_ih, W_hh, gpart);
  lstm_kernel<<<dim3(4, 64), 256, 0, stream>>>(gpart, b_ih, b_hh, c, out);
  fcK2048_kernel<<<500, 512, 0, stream>>>(out + OUT_H1, ctx, fcW, fcb, out);
}

// Round 14
// 259.243 us; speedup vs baseline: 1.3364x; 1.0150x over previous
//
#include <hip/hip_runtime.h>
#include <math.h>

#define VOCAB 32000
#define EMBED 512
#define HID   1024
#define BATCH 64
#define SEQ   512

// d_out layout (floats): pred[64*32000]=0 .. 2048000 ; h1 @2048000 ; c1 @2113536 ; attn @2179072
#define OUT_H1   2048000
#define OUT_C1   2113536
#define OUT_ATTN 2179072

typedef __bf16 bf16x8 __attribute__((ext_vector_type(8)));
typedef float  f32x4  __attribute__((ext_vector_type(4)));

__device__ __forceinline__ unsigned short f2bf(float f) {
  unsigned int u = __builtin_bit_cast(unsigned int, f);
  u += 0x7fffu + ((u >> 16) & 1u);   // round-to-nearest-even
  return (unsigned short)(u >> 16);
}
__device__ __forceinline__ float bf2f(unsigned int u) {
  return __builtin_bit_cast(float, u << 16);
}

// fast tanh: (e^{2x}-1)/(e^{2x}+1) via hw exp2; clamp avoids inf/inf
__device__ __forceinline__ float fast_tanh(float x) {
  float cx = fminf(fmaxf(x, -15.f), 15.f);
  float t = __builtin_amdgcn_exp2f(cx * 2.8853900817779268f);  // e^{2x}
  return (t - 1.f) / (t + 1.f);
}

// async 16B/lane global->LDS; lds ptr must be wave-uniform (HW: base + lane*16)
__device__ __forceinline__ void gload16(const unsigned short* g, unsigned short* l) {
  __builtin_amdgcn_global_load_lds(
      (const __attribute__((address_space(1))) void*)g,
      (__attribute__((address_space(3))) void*)l, 16, 0, 0);
}

// ------------- f32 -> bf16 bulk convert (grid-stride, 8 elems/thread/iter) -------------
__global__ void f2bf_kernel(const float* __restrict__ src, unsigned short* __restrict__ dst,
                            int n8) {
  int i = blockIdx.x * blockDim.x + threadIdx.x;
  int stride = gridDim.x * blockDim.x;
  for (; i < n8; i += stride) {
    const float* s = src + (size_t)i * 8;
    float4 f0 = *(const float4*)s;
    float4 f1 = *(const float4*)(s + 4);
    union { unsigned short us[8]; uint4 u; } p;
    p.us[0]=f2bf(f0.x); p.us[1]=f2bf(f0.y); p.us[2]=f2bf(f0.z); p.us[3]=f2bf(f0.w);
    p.us[4]=f2bf(f1.x); p.us[5]=f2bf(f1.y); p.us[6]=f2bf(f1.z); p.us[7]=f2bf(f1.w);
    *(uint4*)(dst + (size_t)i * 8) = p.u;
  }
}

// ---- dh = h0@W1^T (0..255) + W2->bf16 (256..767) + zero ctx (768..831) ----
__global__ void dh_w2_kernel(const float* __restrict__ h0, const float* __restrict__ W1,
                             float* __restrict__ dh,
                             const float* __restrict__ W2, unsigned short* __restrict__ W2b,
                             float* __restrict__ ctx) {
  __shared__ float hs[HID];
  int bid = blockIdx.x, t = threadIdx.x;
  if (bid < 256) {
    int b = bid >> 2, kblk = bid & 3;
    for (int i = t; i < HID; i += 256) hs[i] = h0[b * HID + i];
    __syncthreads();
    int k = kblk * 256 + t;
    const float* w = W1 + (size_t)k * HID;
    float acc = 0.f;
    for (int hh = 0; hh < HID; hh += 4) {
      float4 wv = *(const float4*)(w + hh);
      float4 hv = *(const float4*)(hs + hh);
      acc += wv.x * hv.x + wv.y * hv.y + wv.z * hv.z + wv.w * hv.w;
    }
    dh[b * HID + k] = acc;
  } else if (bid < 768) {
    int i = (bid - 256) * 256 + t;   // 512*256 = 131072 groups of 8 = HID*HID/8
    const float* s = W2 + (size_t)i * 8;
    float4 f0 = *(const float4*)s;
    float4 f1 = *(const float4*)(s + 4);
    union { unsigned short us[8]; uint4 u; } p;
    p.us[0]=f2bf(f0.x); p.us[1]=f2bf(f0.y); p.us[2]=f2bf(f0.z); p.us[3]=f2bf(f0.w);
    p.us[4]=f2bf(f1.x); p.us[5]=f2bf(f1.y); p.us[6]=f2bf(f1.z); p.us[7]=f2bf(f1.w);
    *(uint4*)(W2b + (size_t)i * 8) = p.u;
  } else {
    int i = (bid - 768) * 256 + t;   // 64*256*4 = 65536 floats
    *(float4*)(ctx + (size_t)i * 4) = (float4){0.f, 0.f, 0.f, 0.f};
  }
}

// ==== scores: 256x256 tile, BK=64, 8 waves, counted-vmcnt pipeline ====
// Epilogue: in-block wc-reduction via LDS, plain store into 4 nt partial
// planes (no atomics, no pre-zero). spart[nt*32768 + global_row].
__launch_bounds__(512, 2)
__global__ void scores8_kernel(const unsigned short* __restrict__ encb,
                               const unsigned short* __restrict__ W2b,
                               const float* __restrict__ dh, const float* __restrict__ v,
                               float* __restrict__ spart) {
  __shared__ __align__(16) unsigned short sA[2][16384];  // [dbuf][256 rows * 64 k]
  __shared__ __align__(16) unsigned short sB[2][16384];
  __shared__ float dh_s[256];
  __shared__ float v_s[256];
  __shared__ float red4[4][256];

  int bid = blockIdx.x;
  int wg = (bid & 7) * 64 + (bid >> 3);
  int mt = wg >> 2, nt = wg & 3;
  int m0 = mt * 256, n0 = nt * 256;

  int t = threadIdx.x;
  int wid = t >> 6, l = t & 63;
  int wr = wid >> 2, wc = wid & 3;     // 2 M-waves x 4 N-waves
  int fr = l & 15, co = (l >> 4) * 8;

  // Stage-source for the (row&7)<<3 elem-swizzle (r11-verified)
  const unsigned short* pa0;
  const unsigned short* pb0;
  int do0 = wid * 512;
  {
    int row0 = wid * 8 + (l >> 3);
    int colE = ((l & 7) ^ ((l >> 3) & 7)) << 3;
    pa0 = encb + (size_t)(m0 + row0) * HID + colE;
    pb0 = W2b + (size_t)(n0 + row0) * HID + colE;
  }

  f32x4 acc[8][4];
#pragma unroll
  for (int i = 0; i < 8; i++)
#pragma unroll
    for (int j = 0; j < 4; j++) acc[i][j] = (f32x4){0.f, 0.f, 0.f, 0.f};

#define SC_STAGE(T, d)                                                         \
  do {                                                                         \
    int k0_ = (T) * 64;                                                        \
    gload16(pa0 + k0_,          &sA[d][do0]);                                  \
    gload16(pa0 + 65536 + k0_,  &sA[d][do0 + 4096]);                           \
    gload16(pa0 + 131072 + k0_, &sA[d][do0 + 8192]);                           \
    gload16(pa0 + 196608 + k0_, &sA[d][do0 + 12288]);                          \
    gload16(pb0 + k0_,          &sB[d][do0]);                                  \
    gload16(pb0 + 65536 + k0_,  &sB[d][do0 + 4096]);                           \
    gload16(pb0 + 131072 + k0_, &sB[d][do0 + 8192]);                           \
    gload16(pb0 + 196608 + k0_, &sB[d][do0 + 12288]);                          \
  } while (0)

  SC_STAGE(0, 0);
  SC_STAGE(1, 1);

  // swizzled ds_read: elem col ^= (row&7)<<3
#define LDF(Mat, row, ks) \
  (*(const bf16x8*)&Mat[(row) * 64 + (((ks) * 32 + co) ^ (((row) & 7) << 3))])

  for (int T = 0; T < 16; ++T) {
    int d = T & 1;
    if (T == 15) asm volatile("s_waitcnt vmcnt(0)" ::: "memory");
    else         asm volatile("s_waitcnt vmcnt(8)" ::: "memory");
    asm volatile("s_barrier" ::: "memory");
    const unsigned short* A = sA[d];
    const unsigned short* B = sB[d];
    bf16x8 a[4][2], b[4][2];
#pragma unroll
    for (int jj = 0; jj < 4; ++jj)
#pragma unroll
      for (int ks = 0; ks < 2; ++ks)
        b[jj][ks] = LDF(B, wc * 64 + jj * 16 + fr, ks);
#pragma unroll
    for (int ii = 0; ii < 4; ++ii)
#pragma unroll
      for (int ks = 0; ks < 2; ++ks)
        a[ii][ks] = LDF(A, wr * 128 + ii * 16 + fr, ks);
    __builtin_amdgcn_s_setprio(1);
#pragma unroll
    for (int ii = 0; ii < 4; ++ii)
#pragma unroll
      for (int jj = 0; jj < 2; ++jj)
#pragma unroll
        for (int ks = 0; ks < 2; ++ks)
          acc[ii][jj] = __builtin_amdgcn_mfma_f32_16x16x32_bf16(a[ii][ks], b[jj][ks], acc[ii][jj], 0, 0, 0);
    __builtin_amdgcn_s_setprio(0);
    __builtin_amdgcn_s_setprio(1);
#pragma unroll
    for (int ii = 0; ii < 4; ++ii)
#pragma unroll
      for (int jj = 2; jj < 4; ++jj)
#pragma unroll
        for (int ks = 0; ks < 2; ++ks)
          acc[ii][jj] = __builtin_amdgcn_mfma_f32_16x16x32_bf16(a[ii][ks], b[jj][ks], acc[ii][jj], 0, 0, 0);
    __builtin_amdgcn_s_setprio(0);
#pragma unroll
    for (int ii = 0; ii < 4; ++ii)
#pragma unroll
      for (int ks = 0; ks < 2; ++ks)
        a[ii][ks] = LDF(A, wr * 128 + 64 + ii * 16 + fr, ks);
    __builtin_amdgcn_s_setprio(1);
#pragma unroll
    for (int ii = 0; ii < 4; ++ii)
#pragma unroll
      for (int jj = 2; jj < 4; ++jj)
#pragma unroll
        for (int ks = 0; ks < 2; ++ks)
          acc[4 + ii][jj] = __builtin_amdgcn_mfma_f32_16x16x32_bf16(a[ii][ks], b[jj][ks], acc[4 + ii][jj], 0, 0, 0);
    __builtin_amdgcn_s_setprio(0);
    __builtin_amdgcn_s_setprio(1);
#pragma unroll
    for (int ii = 0; ii < 4; ++ii)
#pragma unroll
      for (int jj = 0; jj < 2; ++jj)
#pragma unroll
        for (int ks = 0; ks < 2; ++ks)
          acc[4 + ii][jj] = __builtin_amdgcn_mfma_f32_16x16x32_bf16(a[ii][ks], b[jj][ks], acc[4 + ii][jj], 0, 0, 0);
    __builtin_amdgcn_s_setprio(0);
    asm volatile("s_barrier" ::: "memory");   // all reads of dbuf d done
    if (T < 14) SC_STAGE(T + 2, d);           // prefetch tile T+2 into dbuf d
  }
#undef LDF
#undef SC_STAGE

  // epilogue: partial over this wave's 64-wide wc slice (fast_tanh), then
  // LDS-reduce across the 4 wc waves, plain store to plane nt.
  int b = m0 >> 9;
  if (t < 256) { dh_s[t] = dh[b * HID + n0 + t]; v_s[t] = v[n0 + t]; }
  __syncthreads();
  float sp[32];
#pragma unroll
  for (int q = 0; q < 32; ++q) sp[q] = 0.f;
#pragma unroll
  for (int ii = 0; ii < 8; ++ii)
#pragma unroll
    for (int jj = 0; jj < 4; ++jj) {
      int nl = wc * 64 + jj * 16 + fr;
      float dv = dh_s[nl], vv = v_s[nl];
#pragma unroll
      for (int r = 0; r < 4; ++r)
        sp[ii * 4 + r] += fast_tanh(dv + acc[ii][jj][r]) * vv;
    }
#pragma unroll
  for (int q = 0; q < 32; ++q) {
    float x = sp[q];
    x += __shfl_xor(x, 1);
    x += __shfl_xor(x, 2);
    x += __shfl_xor(x, 4);
    x += __shfl_xor(x, 8);
    sp[q] = x;
  }
  if (fr == 0) {
    int rl = wr * 128 + (l >> 4) * 4;   // local row base
#pragma unroll
    for (int ii = 0; ii < 8; ++ii)
#pragma unroll
      for (int r = 0; r < 4; ++r)
        red4[wc][rl + ii * 16 + r] = sp[ii * 4 + r];
  }
  __syncthreads();
  if (t < 256)
    spart[nt * 32768 + m0 + t] = red4[0][t] + red4[1][t] + red4[2][t] + red4[3][t];
}

// ---- context (softmax fused): each block recomputes row softmax stats from
// spart (L2-resident, 512KB), writes its attn slice (blocks s0==0 write the
// whole row), and accumulates ctx for its 64-s slice. ----
__global__ void context2f_kernel(const unsigned short* __restrict__ encb,
                                 const float* __restrict__ spart,
                                 float* __restrict__ attn, float* __restrict__ ctx) {
  __shared__ float a_s[64];
  __shared__ float red[4];
  int b = blockIdx.y, s0 = blockIdx.x * 64, t = threadIdx.x;  // 256 threads

  // row stats: thread t handles s = t (x0) and s = t+256 (x1)
  int r0 = b * SEQ + t, r1 = r0 + 256;
  float x0 = spart[r0] + spart[32768 + r0] + spart[65536 + r0] + spart[98304 + r0];
  float x1 = spart[r1] + spart[32768 + r1] + spart[65536 + r1] + spart[98304 + r1];
  float m = fmaxf(x0, x1);
  for (int d = 1; d < 64; d <<= 1) m = fmaxf(m, __shfl_xor(m, d));
  if ((t & 63) == 0) red[t >> 6] = m;
  __syncthreads();
  float bm = fmaxf(fmaxf(red[0], red[1]), fmaxf(red[2], red[3]));
  float e0 = expf(x0 - bm), e1 = expf(x1 - bm);
  float s = e0 + e1;
  for (int d = 1; d < 64; d <<= 1) s += __shfl_xor(s, d);
  __syncthreads();
  if ((t & 63) == 0) red[t >> 6] = s;
  __syncthreads();
  float bs = red[0] + red[1] + red[2] + red[3];
  float inv = 1.f / bs;
  if (s0 == 0) {   // one block per b writes the attn output row
    attn[b * SEQ + t] = e0 * inv;
    attn[b * SEQ + 256 + t] = e1 * inv;
  }
  // this block's 64-wide attn slice, from the registers that hold it
  if ((t & 255) >= s0 && (t & 255) < s0 + 64) a_s[t - s0] = e0 * inv;
  int s1i = t + 256;
  if (s1i >= s0 && s1i < s0 + 64) a_s[s1i - s0] = e1 * inv;
  __syncthreads();

  int hg = (t & 127) * 8, sg = (t >> 7) * 32;  // 128 h-threads x 2 s-groups
  float a0 = 0.f, a1 = 0.f, a2 = 0.f, a3 = 0.f, a4 = 0.f, a5 = 0.f, a6 = 0.f, a7 = 0.f;
  const unsigned short* base = encb + ((size_t)b * SEQ + s0 + sg) * HID + hg;
  for (int ss = 0; ss < 32; ss++) {
    uint4 ev = *(const uint4*)(base + (size_t)ss * HID);
    float a = a_s[sg + ss];
    a0 += a * bf2f(ev.x & 0xffffu); a1 += a * bf2f(ev.x >> 16);
    a2 += a * bf2f(ev.y & 0xffffu); a3 += a * bf2f(ev.y >> 16);
    a4 += a * bf2f(ev.z & 0xffffu); a5 += a * bf2f(ev.z >> 16);
    a6 += a * bf2f(ev.w & 0xffffu); a7 += a * bf2f(ev.w >> 16);
  }
  atomicAdd(&ctx[b * HID + hg + 0], a0);
  atomicAdd(&ctx[b * HID + hg + 1], a1);
  atomicAdd(&ctx[b * HID + hg + 2], a2);
  atomicAdd(&ctx[b * HID + hg + 3], a3);
  atomicAdd(&ctx[b * HID + hg + 4], a4);
  atomicAdd(&ctx[b * HID + hg + 5], a5);
  atomicAdd(&ctx[b * HID + hg + 6], a6);
  atomicAdd(&ctx[b * HID + hg + 7], a7);
}

// ==== gates via MFMA: gpart[kz] = x @ W[:, kz*320:+320]^T  (M=64, N=4096) ====
__launch_bounds__(256)
__global__ void gates8p_kernel(const int* __restrict__ tok, const float* __restrict__ emb,
                               const float* __restrict__ ctx, const float* __restrict__ h0,
                               const float* __restrict__ W_ih, const float* __restrict__ W_hh,
                               float* __restrict__ gpart) {
  __shared__ __align__(16) unsigned short lA[64 * 40];
  __shared__ __align__(16) unsigned short lB[128 * 40];
  int n0 = blockIdx.x * 128, kz = blockIdx.y;   // 32 n-blocks x 8 K-slices
  int kbase = kz * 320;
  int t = threadIdx.x, w = t >> 6, l = t & 63;
  f32x4 acc[4][2];
#pragma unroll
  for (int i = 0; i < 4; i++)
#pragma unroll
    for (int j = 0; j < 2; j++) acc[i][j] = (f32x4){0.f, 0.f, 0.f, 0.f};
  int rowA = t >> 2, qA = (t & 3) * 8;   // 64 rows x 4 quads of 8
  int rowB = t >> 1, hB = t & 1;         // 128 rows x 2 halves of 16
  int tkA = tok[rowA];

  for (int kt = 0; kt < 10; kt++) {
    int k0 = kbase + kt * 32;
    {  // A stage (segments never cross 512/1536)
      int kg = k0 + qA;
      const float* src;
      if (kg < 512)        src = emb + (size_t)tkA * EMBED + kg;
      else if (kg < 1536)  src = ctx + rowA * HID + (kg - 512);
      else                 src = h0 + rowA * HID + (kg - 1536);
      float4 f0 = *(const float4*)src;
      float4 f1 = *(const float4*)(src + 4);
      union { unsigned short us[8]; uint4 u; } p;
      p.us[0]=f2bf(f0.x); p.us[1]=f2bf(f0.y); p.us[2]=f2bf(f0.z); p.us[3]=f2bf(f0.w);
      p.us[4]=f2bf(f1.x); p.us[5]=f2bf(f1.y); p.us[6]=f2bf(f1.z); p.us[7]=f2bf(f1.w);
      *(uint4*)&lA[rowA * 40 + qA] = p.u;
    }
    {  // B stage (16-seg never crosses 1536)
      int kg = k0 + hB * 16;
      const float* src = (kg < 1536) ? (W_ih + (size_t)(n0 + rowB) * 1536 + kg)
                                     : (W_hh + (size_t)(n0 + rowB) * 1024 + (kg - 1536));
      float4 f0 = *(const float4*)src;
      float4 f1 = *(const float4*)(src + 4);
      float4 f2 = *(const float4*)(src + 8);
      float4 f3 = *(const float4*)(src + 12);
      union { unsigned short us[16]; uint4 u4[2]; } p;
      p.us[0]=f2bf(f0.x);  p.us[1]=f2bf(f0.y);  p.us[2]=f2bf(f0.z);  p.us[3]=f2bf(f0.w);
      p.us[4]=f2bf(f1.x);  p.us[5]=f2bf(f1.y);  p.us[6]=f2bf(f1.z);  p.us[7]=f2bf(f1.w);
      p.us[8]=f2bf(f2.x);  p.us[9]=f2bf(f2.y);  p.us[10]=f2bf(f2.z); p.us[11]=f2bf(f2.w);
      p.us[12]=f2bf(f3.x); p.us[13]=f2bf(f3.y); p.us[14]=f2bf(f3.z); p.us[15]=f2bf(f3.w);
      *(uint4*)&lB[rowB * 40 + hB * 16 + 0] = p.u4[0];
      *(uint4*)&lB[rowB * 40 + hB * 16 + 8] = p.u4[1];
    }
    __syncthreads();
    bf16x8 af[4], bv[2];
    int co = (l >> 4) * 8;
#pragma unroll
    for (int i = 0; i < 4; i++) af[i] = *(const bf16x8*)&lA[(i * 16 + (l & 15)) * 40 + co];
#pragma unroll
    for (int j = 0; j < 2; j++) bv[j] = *(const bf16x8*)&lB[(w * 32 + j * 16 + (l & 15)) * 40 + co];
#pragma unroll
    for (int i = 0; i < 4; i++)
#pragma unroll
      for (int j = 0; j < 2; j++)
        acc[i][j] = __builtin_amdgcn_mfma_f32_16x16x32_bf16(af[i], bv[j], acc[i][j], 0, 0, 0);
    __syncthreads();
  }
#pragma unroll
  for (int i = 0; i < 4; i++)
#pragma unroll
    for (int j = 0; j < 2; j++) {
      int n = n0 + w * 32 + j * 16 + (l & 15);
#pragma unroll
      for (int r = 0; r < 4; r++) {
        int m = i * 16 + (l >> 4) * 4 + r;
        gpart[(size_t)kz * 262144 + (size_t)m * 4096 + n] = acc[i][j][r];
      }
    }
}

// ------- LSTM pointwise (fused 8-plane gate combine) -> h1, c1 -------
__global__ void lstm_kernel(const float* __restrict__ gpart, const float* __restrict__ b_ih,
                            const float* __restrict__ b_hh, const float* __restrict__ c0,
                            float* __restrict__ out) {
  int b = blockIdx.y;
  int hh = blockIdx.x * 256 + threadIdx.x;
  float gi = b_ih[hh]        + b_hh[hh];
  float gf = b_ih[1024 + hh] + b_hh[1024 + hh];
  float gg = b_ih[2048 + hh] + b_hh[2048 + hh];
  float go = b_ih[3072 + hh] + b_hh[3072 + hh];
#pragma unroll
  for (int kz = 0; kz < 8; kz++) {
    const float* g = gpart + (size_t)kz * 262144 + (size_t)b * 4096;
    gi += g[hh];
    gf += g[1024 + hh];
    gg += g[2048 + hh];
    go += g[3072 + hh];
  }
  float si = 1.f / (1.f + expf(-gi));
  float sf = 1.f / (1.f + expf(-gf));
  float so = 1.f / (1.f + expf(-go));
  float c1 = sf * c0[b * HID + hh] + si * tanhf(gg);
  float h1 = so * tanhf(c1);
  out[OUT_H1 + b * HID + hh] = h1;
  out[OUT_C1 + b * HID + hh] = c1;
}

// ---- fc: full K=2048 per block, 500 blocks x 512 threads, direct pred write ----
__launch_bounds__(512)
__global__ void fcK2048_kernel(const float* __restrict__ h1, const float* __restrict__ ctx,
                               const float* __restrict__ fcW, const float* __restrict__ fcb,
                               float* __restrict__ pred) {
  __shared__ __align__(16) unsigned short lA[64 * 72];  // 64 rows x 64 k, pad 72
  __shared__ __align__(16) unsigned short lB[64 * 72];
  int n0 = blockIdx.x * 64;
  int t = threadIdx.x, w = t >> 6, l = t & 63;
  int wr = w >> 2, wc = w & 3;         // 2 M-halves x 4 N-quarters
  int fr = l & 15, co = (l >> 4) * 8;
  f32x4 acc[2];
  acc[0] = (f32x4){0.f, 0.f, 0.f, 0.f};
  acc[1] = (f32x4){0.f, 0.f, 0.f, 0.f};
  int rowS = t >> 3, qS = (t & 7) * 8;   // 64 rows x 8 quads of 8 (BK=64)

  for (int kt = 0; kt < 32; kt++) {
    int k0 = kt * 64;
    {  // A stage: x = [h1 | ctx], 8-seg never crosses the 1024 boundary
      int kg = k0 + qS;
      const float* src = (kg < 1024) ? (h1 + rowS * HID + kg) : (ctx + rowS * HID + kg - 1024);
      float4 f0 = *(const float4*)src;
      float4 f1 = *(const float4*)(src + 4);
      union { unsigned short us[8]; uint4 u; } p;
      p.us[0]=f2bf(f0.x); p.us[1]=f2bf(f0.y); p.us[2]=f2bf(f0.z); p.us[3]=f2bf(f0.w);
      p.us[4]=f2bf(f1.x); p.us[5]=f2bf(f1.y); p.us[6]=f2bf(f1.z); p.us[7]=f2bf(f1.w);
      *(uint4*)&lA[rowS * 72 + qS] = p.u;
    }
    {  // B stage
      const float* src = fcW + (size_t)(n0 + rowS) * 2048 + k0 + qS;
      float4 f0 = *(const float4*)src;
      float4 f1 = *(const float4*)(src + 4);
      union { unsigned short us[8]; uint4 u; } p;
      p.us[0]=f2bf(f0.x); p.us[1]=f2bf(f0.y); p.us[2]=f2bf(f0.z); p.us[3]=f2bf(f0.w);
      p.us[4]=f2bf(f1.x); p.us[5]=f2bf(f1.y); p.us[6]=f2bf(f1.z); p.us[7]=f2bf(f1.w);
      *(uint4*)&lB[rowS * 72 + qS] = p.u;
    }
    __syncthreads();
    bf16x8 a0, a1, bv;
#pragma unroll
    for (int ks = 0; ks < 2; ks++) {
      a0 = *(const bf16x8*)&lA[(wr * 32 + fr) * 72 + ks * 32 + co];
      a1 = *(const bf16x8*)&lA[(wr * 32 + 16 + fr) * 72 + ks * 32 + co];
      bv = *(const bf16x8*)&lB[(wc * 16 + fr) * 72 + ks * 32 + co];
      acc[0] = __builtin_amdgcn_mfma_f32_16x16x32_bf16(a0, bv, acc[0], 0, 0, 0);
      acc[1] = __builtin_amdgcn_mfma_f32_16x16x32_bf16(a1, bv, acc[1], 0, 0, 0);
    }
    __syncthreads();
  }
  int n = n0 + wc * 16 + fr;
  float bias = fcb[n];
#pragma unroll
  for (int i = 0; i < 2; i++) {
#pragma unroll
    for (int r = 0; r < 4; r++) {
      int m = wr * 32 + i * 16 + (l >> 4) * 4 + r;
      pred[(size_t)m * VOCAB + n] = acc[i][r] + bias;
    }
  }
}

extern "C" void kernel_launch(void* const* d_in, const int* in_sizes, int n_in,
                              void* d_out, int out_size, void* d_ws, size_t ws_size,
                              hipStream_t stream) {
  const int*   tok  = (const int*)d_in[0];
  const float* h    = (const float*)d_in[1];
  const float* c    = (const float*)d_in[2];
  const float* enc  = (const float*)d_in[3];
  const float* emb  = (const float*)d_in[4];
  const float* W1   = (const float*)d_in[5];
  const float* W2   = (const float*)d_in[6];
  const float* v    = (const float*)d_in[7];
  const float* W_ih = (const float*)d_in[8];
  const float* W_hh = (const float*)d_in[9];
  const float* b_ih = (const float*)d_in[10];
  const float* b_hh = (const float*)d_in[11];
  const float* fcW  = (const float*)d_in[12];
  const float* fcb  = (const float*)d_in[13];
  float* out = (float*)d_out;

  float* wsf    = (float*)d_ws;
  float* spart  = wsf;             // 4*32768 = 131072
  float* ctx    = wsf + 131072;    // 65536
  float* dh     = wsf + 196608;    // 65536
  float* gpart  = wsf + 262144;    // 8*262144 = 2097152
  unsigned short* encb = (unsigned short*)(wsf + 2359296);   // 33,554,432 bf16
  unsigned short* W2b  = encb + (size_t)BATCH * SEQ * HID;   //  1,048,576 bf16

  f2bf_kernel<<<2048, 256, 0, stream>>>(enc, encb, BATCH * SEQ * HID / 8);
  dh_w2_kernel<<<832, 256, 0, stream>>>(h, W1, dh, W2, W2b, ctx);
  scores8_kernel<<<512, 512, 0, stream>>>(encb, W2b, dh, v, spart);
  context2f_kernel<<<dim3(8, 64), 256, 0, stream>>>(encb, spart, out + OUT_ATTN, ctx);
  gates8p_kernel<<<dim3(32, 8), 256, 0, stream>>>(tok, emb, ctx, h, W_ih, W_hh, gpart);
  lstm_kernel<<<dim3(4, 64), 256, 0, stream>>>(gpart, b_ih, b_hh, c, out);
  fcK2048_kernel<<<500, 512, 0, stream>>>(out + OUT_H1, ctx, fcW, fcb, out);
}